// Round 9
// baseline (279.899 us; speedup 1.0000x reference)
//
#include <hip/hip_runtime.h>
#include <math.h>

#define TSEQ 2048
#define DM   768
#define NH   12
#define HD   64
#define NBH  24
#define WN   589824  // 768*768

typedef __attribute__((ext_vector_type(8))) short short8;
typedef __attribute__((ext_vector_type(4))) float f32x4;

#define MFMA_BF16(a, b, c) __builtin_amdgcn_mfma_f32_16x16x32_bf16(a, b, c, 0, 0, 0)

// round(linspace(0, 2047, 32)) — verified against fp32 evaluation (no .5 ties)
__constant__ int c_idxp[32] = {0,66,132,198,264,330,396,462,528,594,660,726,
  792,858,924,990,1057,1123,1189,1255,1321,1387,1453,1519,1585,1651,1717,1783,
  1849,1915,1981,2047};

// ---- DPP helpers: row(16-lane)-local rotations on the VALU pipe ----
template <int CTRL>
__device__ __forceinline__ float dppf(float x) {
  return __int_as_float(__builtin_amdgcn_mov_dpp(__float_as_int(x), CTRL, 0xF, 0xF, true));
}
template <int CTRL>
__device__ __forceinline__ int dppi(int x) {
  return __builtin_amdgcn_mov_dpp(x, CTRL, 0xF, 0xF, true);
}
__device__ __forceinline__ float wsum(float v) {
  v += dppf<0x121>(v);
  v += dppf<0x122>(v);
  v += dppf<0x124>(v);
  v += dppf<0x128>(v);
  v += __shfl_xor(v, 16, 64);
  v += __shfl_xor(v, 32, 64);
  return v;
}
__device__ __forceinline__ float wmaxr(float v) {
  v = fmaxf(v, dppf<0x121>(v));
  v = fmaxf(v, dppf<0x122>(v));
  v = fmaxf(v, dppf<0x124>(v));
  v = fmaxf(v, dppf<0x128>(v));
  v = fmaxf(v, __shfl_xor(v, 16, 64));
  v = fmaxf(v, __shfl_xor(v, 32, 64));
  return v;
}

__device__ __forceinline__ ushort bf16rne(float x) {
  unsigned u = __float_as_uint(x);
  return (ushort)((u + 0x7fffu + ((u >> 16) & 1u)) >> 16);
}

// split 8 fp32 -> bf16 h/m/l (RNE each stage; subtractions exact)
template <bool NEED_L>
__device__ __forceinline__ void split_store(const float4& v0, const float4& v1,
                                            ushort* ph, ushort* pm, ushort* pl) {
  float xs[8] = {v0.x, v0.y, v0.z, v0.w, v1.x, v1.y, v1.z, v1.w};
  short8 h, m, l;
#pragma unroll
  for (int j = 0; j < 8; ++j) {
    float x = xs[j];
    ushort hb = bf16rne(x);
    h[j] = (short)hb;
    float d = x - __uint_as_float((unsigned)hb << 16);
    ushort mb = bf16rne(d);
    m[j] = (short)mb;
    if (NEED_L) {
      float d2 = d - __uint_as_float((unsigned)mb << 16);
      l[j] = (short)bf16rne(d2);
    }
  }
  *(short8*)ph = h;
  *(short8*)pm = m;
  if (NEED_L) *(short8*)pl = l;
}

// Swizzled LDS layout: tile stored as 128B lines (64 ushort) of 8 x 16B chunks,
// chunk' = chunk8 ^ (line&7). Conflict-free for staging writes and
// 16-lane x b128 fragment reads (one lane per bank-quad per line).
__device__ __forceinline__ int lds_idx(int row, int chunk /*0..3*/) {
  int line = row >> 1;
  int c8 = ((row & 1) << 2) | chunk;
  return line * 64 + ((c8 ^ (line & 7)) << 3);
}

// -------- pre-split: z=0 X -> Xh/Xm/Xl, z=1..4 W -> wsp[mi][lvl][WN] --------
__global__ __launch_bounds__(256) void convert_kernel(
    const float* __restrict__ x,
    const float* __restrict__ W0, const float* __restrict__ W1,
    const float* __restrict__ W2, const float* __restrict__ W3,
    ushort* __restrict__ Xh, ushort* __restrict__ Xm, ushort* __restrict__ Xl,
    ushort* __restrict__ wsp) {
  int z = blockIdx.y;
  size_t base = (size_t)(blockIdx.x * 256 + threadIdx.x) * 8;
  if (z == 0) {
    float4 v0 = *(const float4*)(x + base);
    float4 v1 = *(const float4*)(x + base + 4);
    split_store<true>(v0, v1, Xh + base, Xm + base, Xl + base);
  } else {
    if (base >= WN) return;
    int mi = z - 1;
    const float* s = (mi == 0) ? W0 : (mi == 1) ? W1 : (mi == 2) ? W2 : W3;
    ushort* h = wsp + (size_t)mi * 3 * WN;
    float4 v0 = *(const float4*)(s + base);
    float4 v1 = *(const float4*)(s + base + 4);
    split_store<true>(v0, v1, h + base, h + WN + base, h + 2 * WN + base);
  }
}

// ---------------- split-bf16 MFMA GEMM: dst = (A @ B^T + bias) * scale ------
// A and B pre-split bf16 h/m/l in global (staging = pure short8 copies).
// 128x128 tile, BK=32, 256 thr = 4 waves (2Mx2N), per wave 4x4 16x16x32 frags.
// Product order per acc element: hh,mh,hm(,mm,lh,hl) — bit-identical to R8.
template <int MODE, int NPROD>
__device__ __forceinline__ void gemm_mfma_body(
    const ushort* __restrict__ Agh, const ushort* __restrict__ Agm,
    const ushort* __restrict__ Agl,
    const ushort* __restrict__ Bgh, const ushort* __restrict__ Bgm,
    const ushort* __restrict__ Bgl,
    const float* __restrict__ bias, float* __restrict__ dst, float scale,
    int mblk, int nblk, ushort* lds) {
  const int tid = threadIdx.x;
  const int lane = tid & 63;
  const int w = tid >> 6;
  const int wr = w >> 1, wc = w & 1;
  const int lrow = lane & 15, kq = lane >> 4;
  constexpr int BUF = 4096;  // 128 rows x 32 ushort (64 lines x 64)
  ushort* Ahs = lds;
  ushort* Ams = Ahs + BUF;
  ushort* Als = (NPROD == 6) ? (Ams + BUF) : nullptr;
  ushort* Bhs = (NPROD == 6) ? (lds + 3 * BUF) : (lds + 2 * BUF);
  ushort* Bms = Bhs + BUF;
  ushort* Bls = (NPROD == 6) ? (Bms + BUF) : nullptr;

  const int srow0 = tid >> 2, srow1 = 64 + (tid >> 2);
  const int achk = tid & 3;
  const int off0 = lds_idx(srow0, achk);
  const int off1 = lds_idx(srow1, achk);
  const size_t a0 = (size_t)(mblk + srow0) * DM + achk * 8;
  const size_t a1 = (size_t)(mblk + srow1) * DM + achk * 8;
  const size_t b0 = (size_t)(nblk + srow0) * DM + achk * 8;
  const size_t b1 = (size_t)(nblk + srow1) * DM + achk * 8;

  f32x4 acc[4][4];
#pragma unroll
  for (int i = 0; i < 4; ++i)
#pragma unroll
    for (int j = 0; j < 4; ++j) {
      f32x4 z = {0.f, 0.f, 0.f, 0.f};
      acc[i][j] = z;
    }

  short8 pah0 = *(const short8*)(Agh + a0), pah1 = *(const short8*)(Agh + a1);
  short8 pam0 = *(const short8*)(Agm + a0), pam1 = *(const short8*)(Agm + a1);
  short8 pal0, pal1;
  if (NPROD == 6) { pal0 = *(const short8*)(Agl + a0); pal1 = *(const short8*)(Agl + a1); }
  short8 pbh0 = *(const short8*)(Bgh + b0), pbh1 = *(const short8*)(Bgh + b1);
  short8 pbm0 = *(const short8*)(Bgm + b0), pbm1 = *(const short8*)(Bgm + b1);
  short8 pbl0, pbl1;
  if (NPROD == 6) { pbl0 = *(const short8*)(Bgl + b0); pbl1 = *(const short8*)(Bgl + b1); }

  for (int k0 = 0; k0 < DM; k0 += 32) {
    __syncthreads();
    *(short8*)&Ahs[off0] = pah0; *(short8*)&Ahs[off1] = pah1;
    *(short8*)&Ams[off0] = pam0; *(short8*)&Ams[off1] = pam1;
    if (NPROD == 6) { *(short8*)&Als[off0] = pal0; *(short8*)&Als[off1] = pal1; }
    *(short8*)&Bhs[off0] = pbh0; *(short8*)&Bhs[off1] = pbh1;
    *(short8*)&Bms[off0] = pbm0; *(short8*)&Bms[off1] = pbm1;
    if (NPROD == 6) { *(short8*)&Bls[off0] = pbl0; *(short8*)&Bls[off1] = pbl1; }
    __syncthreads();
    if (k0 + 32 < DM) {  // prefetch next K-tile; overlaps MFMA
      pah0 = *(const short8*)(Agh + a0 + k0 + 32);
      pah1 = *(const short8*)(Agh + a1 + k0 + 32);
      pam0 = *(const short8*)(Agm + a0 + k0 + 32);
      pam1 = *(const short8*)(Agm + a1 + k0 + 32);
      if (NPROD == 6) {
        pal0 = *(const short8*)(Agl + a0 + k0 + 32);
        pal1 = *(const short8*)(Agl + a1 + k0 + 32);
      }
      pbh0 = *(const short8*)(Bgh + b0 + k0 + 32);
      pbh1 = *(const short8*)(Bgh + b1 + k0 + 32);
      pbm0 = *(const short8*)(Bgm + b0 + k0 + 32);
      pbm1 = *(const short8*)(Bgm + b1 + k0 + 32);
      if (NPROD == 6) {
        pbl0 = *(const short8*)(Bgl + b0 + k0 + 32);
        pbl1 = *(const short8*)(Bgl + b1 + k0 + 32);
      }
    }
    short8 afh[4], afm[4], afl[4];
#pragma unroll
    for (int fi = 0; fi < 4; ++fi) {
      int o = lds_idx(wr * 64 + fi * 16 + lrow, kq);
      afh[fi] = *(const short8*)&Ahs[o];
      afm[fi] = *(const short8*)&Ams[o];
      if (NPROD == 6) afl[fi] = *(const short8*)&Als[o];
    }
#pragma unroll
    for (int fj = 0; fj < 4; ++fj) {
      int o = lds_idx(wc * 64 + fj * 16 + lrow, kq);
      short8 bfh = *(const short8*)&Bhs[o];
      short8 bfm = *(const short8*)&Bms[o];
      short8 bfl;
      if (NPROD == 6) bfl = *(const short8*)&Bls[o];
#pragma unroll
      for (int fi = 0; fi < 4; ++fi) {
        acc[fi][fj] = MFMA_BF16(afh[fi], bfh, acc[fi][fj]);
        acc[fi][fj] = MFMA_BF16(afm[fi], bfh, acc[fi][fj]);
        acc[fi][fj] = MFMA_BF16(afh[fi], bfm, acc[fi][fj]);
        if (NPROD == 6) {
          acc[fi][fj] = MFMA_BF16(afm[fi], bfm, acc[fi][fj]);
          acc[fi][fj] = MFMA_BF16(afl[fi], bfh, acc[fi][fj]);
          acc[fi][fj] = MFMA_BF16(afh[fi], bfl, acc[fi][fj]);
        }
      }
    }
  }

#pragma unroll
  for (int fj = 0; fj < 4; ++fj) {
    int col = nblk + wc * 64 + fj * 16 + lrow;
    float bv = bias[col];
#pragma unroll
    for (int fi = 0; fi < 4; ++fi) {
#pragma unroll
      for (int reg = 0; reg < 4; ++reg) {
        int row = mblk + wr * 64 + fi * 16 + kq * 4 + reg;
        float o = (acc[fi][fj][reg] + bv) * scale;
        if (MODE == 0) {
          dst[(size_t)row * DM + col] = o;
        } else {
          int b_ = row >> 11, t = row & (TSEQ - 1);
          int h = col >> 6, dd = col & 63;
          dst[(((size_t)(b_ * NH + h)) * TSEQ + t) * HD + dd] = o;
        }
      }
    }
  }
}

// merged q/k/v projection, XCD-swizzled: z = 0 (q), 1 (k) NPROD6; 2 (v) NPROD3
__global__ __launch_bounds__(256) void qkv_kernel(
    const ushort* __restrict__ Xh, const ushort* __restrict__ Xm,
    const ushort* __restrict__ Xl, const ushort* __restrict__ wsp,
    const float* __restrict__ bq, float* __restrict__ qd,
    const float* __restrict__ bk, float* __restrict__ kd,
    const float* __restrict__ bv, float* __restrict__ vd) {
  __shared__ ushort lds[6 * 4096];  // 48 KB
  // bijective XCD swizzle: 576 blocks, 72 consecutive work items per XCD
  int lid = blockIdx.x + 6 * blockIdx.y + 192 * blockIdx.z;
  int swz = (lid & 7) * 72 + (lid >> 3);
  int z = swz / 192;
  int rem = swz - z * 192;
  int wy = rem / 6, wx = rem - wy * 6;
  const ushort* Bb = wsp + (size_t)z * 3 * WN;
  if (z == 2) {
    gemm_mfma_body<1, 3>(Xh, Xm, nullptr, Bb, Bb + WN, nullptr,
                         bv, vd, 1.0f, wy * 128, wx * 128, lds);
  } else {
    gemm_mfma_body<1, 6>(Xh, Xm, Xl, Bb, Bb + WN, Bb + 2 * WN,
                         z ? bk : bq, z ? kd : qd, z ? 1.0f : 0.125f,
                         wy * 128, wx * 128, lds);
  }
}

__global__ __launch_bounds__(256) void oproj_kernel(
    const ushort* __restrict__ Ph, const ushort* __restrict__ Pm,
    const ushort* __restrict__ wsp,
    const float* __restrict__ bias, float* __restrict__ dst) {
  __shared__ ushort lds[4 * 4096];  // 32 KB
  // bijective XCD swizzle: 192 blocks, 24 per XCD
  int lid = blockIdx.x + 6 * blockIdx.y;
  int swz = (lid & 7) * 24 + (lid >> 3);
  int wy = swz / 6, wx = swz - wy * 6;
  const ushort* Bb = wsp + (size_t)3 * 3 * WN;
  gemm_mfma_body<0, 3>(Ph, Pm, nullptr, Bb, Bb + WN, nullptr,
                       bias, dst, 1.0f, wy * 128, wx * 128, lds);
}

// ---------------- window selection: one wave per (bh, t) ----------------
__global__ __launch_bounds__(256) void window_kernel(
    const float* __restrict__ q, const float* __restrict__ k,
    int* __restrict__ sel) {
  int wid = blockIdx.x * 4 + (threadIdx.x >> 6);
  int lane = threadIdx.x & 63;
  int f = lane & 15, kq = lane >> 4;
  int bh = wid >> 11, t = wid & (TSEQ - 1);
  int start = t - 8;
  if (start < 0) start = 0;
  if (start > TSEQ - 16) start = TSEQ - 16;

  const float* kp = k + ((size_t)bh * TSEQ + start + f) * HD + kq * 8;
  const float* qp = q + ((size_t)bh * TSEQ + t) * HD + kq * 8;
  float kv[16], qv[16];
  *(float4*)&kv[0]  = *(const float4*)(kp + 0);
  *(float4*)&kv[4]  = *(const float4*)(kp + 4);
  *(float4*)&kv[8]  = *(const float4*)(kp + 32);
  *(float4*)&kv[12] = *(const float4*)(kp + 36);
  *(float4*)&qv[0]  = *(const float4*)(qp + 0);
  *(float4*)&qv[4]  = *(const float4*)(qp + 4);
  *(float4*)&qv[8]  = *(const float4*)(qp + 32);
  *(float4*)&qv[12] = *(const float4*)(qp + 36);

  float sp = 0.f, np = 0.f;
#pragma unroll
  for (int i = 0; i < 16; ++i) { sp = fmaf(qv[i], kv[i], sp); np = fmaf(kv[i], kv[i], np); }
  sp += __shfl_xor(sp, 16, 64); sp += __shfl_xor(sp, 32, 64);
  np += __shfl_xor(np, 16, 64); np += __shfl_xor(np, 32, 64);
  float nrm = fmaxf(sqrtf(np), 1e-6f);
  float kn[16];
#pragma unroll
  for (int i = 0; i < 16; ++i) kn[i] = kv[i] / nrm;

  short8 h0, m0, l0, h1, m1, l1;
#pragma unroll
  for (int j = 0; j < 8; ++j) {
    float x = kn[j];
    ushort hb = bf16rne(x); h0[j] = (short)hb;
    float d = x - __uint_as_float((unsigned)hb << 16);
    ushort mb = bf16rne(d); m0[j] = (short)mb;
    l0[j] = (short)bf16rne(d - __uint_as_float((unsigned)mb << 16));
    x = kn[8 + j];
    hb = bf16rne(x); h1[j] = (short)hb;
    d = x - __uint_as_float((unsigned)hb << 16);
    mb = bf16rne(d); m1[j] = (short)mb;
    l1[j] = (short)bf16rne(d - __uint_as_float((unsigned)mb << 16));
  }
  f32x4 g = {0.f, 0.f, 0.f, 0.f};
  g = MFMA_BF16(h0, h0, g); g = MFMA_BF16(h1, h1, g);
  g = MFMA_BF16(m0, h0, g); g = MFMA_BF16(m1, h1, g);
  g = MFMA_BF16(h0, m0, g); g = MFMA_BF16(h1, m1, g);
  g = MFMA_BF16(m0, m0, g); g = MFMA_BF16(m1, m1, g);
  g = MFMA_BF16(l0, h0, g); g = MFMA_BF16(l1, h1, g);
  g = MFMA_BF16(h0, l0, g); g = MFMA_BF16(h1, l1, g);

  int dist = start + f - t; if (dist < 0) dist = -dist;
  float tmp = sp + 0.2f * expf(-(float)dist * 0.125f);

  int* selp = sel + ((size_t)bh * TSEQ + t) * 6;
#pragma unroll
  for (int r = 0; r < 6; ++r) {
    float best = tmp; int bj = f;
    {
      float ov = dppf<0x121>(best); int oi = dppi<0x121>(bj);
      if (ov > best || (ov == best && oi < bj)) { best = ov; bj = oi; }
      ov = dppf<0x122>(best); oi = dppi<0x122>(bj);
      if (ov > best || (ov == best && oi < bj)) { best = ov; bj = oi; }
      ov = dppf<0x124>(best); oi = dppi<0x124>(bj);
      if (ov > best || (ov == best && oi < bj)) { best = ov; bj = oi; }
      ov = dppf<0x128>(best); oi = dppi<0x128>(bj);
      if (ov > best || (ov == best && oi < bj)) { best = ov; bj = oi; }
    }
    if (lane == 0) selp[r] = start + bj;
    if (r < 5) {
      float s01 = (bj & 1) ? g[1] : g[0];
      float s23 = (bj & 1) ? g[3] : g[2];
      float gsel = (bj & 2) ? s23 : s01;
      float grow = __shfl(gsel, ((bj >> 2) << 4) | f, 64);
      tmp -= 0.2f * fmaxf(grow, 0.f);
    }
    if (f == bj) tmp = -1e9f;
  }
}

// ---------------- prototype queries Qp[a][p][:] ----------------
__global__ __launch_bounds__(256) void qp_kernel(const float* __restrict__ q,
                                                 float* __restrict__ Qp) {
  int wid = blockIdx.x * 4 + (threadIdx.x >> 6);
  int lane = threadIdx.x & 63;
  int a = wid >> 5, p = wid & 31;
  int t = c_idxp[p];
  float v = 0.5f * (q[((size_t)(2 * a) * TSEQ + t) * HD + lane] +
                    q[((size_t)(2 * a + 1) * TSEQ + t) * HD + lane]);
  float n2 = wsum(v * v);
  float nrm = fmaxf(sqrtf(n2), 1e-6f);
  Qp[((size_t)a * 32 + p) * HD + lane] = v / nrm;
}

// ---------------- S[a][t][p] and u[a][t] ----------------
__global__ __launch_bounds__(256) void proto_score_kernel(
    const float* __restrict__ k, const float* __restrict__ Qp,
    float* __restrict__ S, float* __restrict__ u) {
  int a = blockIdx.y;
  __shared__ float Qs[2048];
  for (int i = threadIdx.x; i < 2048; i += 256) Qs[i] = Qp[(size_t)a * 2048 + i];
  __syncthreads();
  int w = threadIdx.x >> 6, lane = threadIdx.x & 63;
  int t = blockIdx.x * 4 + w;
  float km = 0.5f * (k[((size_t)(2 * a) * TSEQ + t) * HD + lane] +
                     k[((size_t)(2 * a + 1) * TSEQ + t) * HD + lane]);
  float n2 = wsum(km * km);
  float nrm = fmaxf(sqrtf(n2), 1e-6f);
  float kb = km / nrm;
  float sval = 0.f;
#pragma unroll
  for (int p = 0; p < 32; ++p) {
    float dg = wsum(kb * Qs[p * 64 + lane]);
    dg = fmaxf(dg, 0.f);
    sval = (lane == p) ? dg : sval;
  }
  if (lane < 32) S[((size_t)a * TSEQ + t) * 32 + lane] = sval;
  float x = (lane < 32) ? sval : 0.f;
  float mean = wsum(x) / 32.0f;
  float mx = wmaxr((lane < 32) ? sval : -1e30f);
  float cur = (lane < 32) ? sval : -1e30f;
  float topsum = 0.f;
#pragma unroll
  for (int r = 0; r < 6; ++r) {
    float m = wmaxr(cur);
    topsum += m;
    unsigned long long ball = __ballot(cur == m);
    int first = __ffsll(ball) - 1;
    if (lane == first) cur = -1e30f;
  }
  float dev = (lane < 32) ? (sval - mean) : 0.f;
  float sd = sqrtf(wsum(dev * dev) / 31.0f);
  float uval = ((1.0f * mean + 0.6f * mx) + 0.4f * (topsum / 6.0f)) + 0.2f * sd;
  if (lane == 0) u[(size_t)a * TSEQ + t] = uval;
}

// ---------------- per-head top-12 + greedy facility location ----------------
__global__ void head_select_kernel(const float* __restrict__ u,
                                   const float* __restrict__ S,
                                   int* __restrict__ glob) {
  int a = blockIdx.x;
  int lane = threadIdx.x;
  float uv[32];
#pragma unroll
  for (int c = 0; c < 32; ++c) uv[c] = u[(size_t)a * TSEQ + c * 64 + lane];
  unsigned removed = 0;
  int tidx = 0;
#pragma unroll
  for (int r = 0; r < 12; ++r) {
    float best = -1e30f; int bidx = 1 << 30;
#pragma unroll
    for (int c = 0; c < 32; ++c) {
      if (!((removed >> c) & 1u)) {
        float vv = uv[c]; int gi = c * 64 + lane;
        if (vv > best || (vv == best && gi < bidx)) { best = vv; bidx = gi; }
      }
    }
#pragma unroll
    for (int mS = 1; mS < 64; mS <<= 1) {
      float ov = __shfl_xor(best, mS, 64);
      int oi = __shfl_xor(bidx, mS, 64);
      if (ov > best || (ov == best && oi < bidx)) { best = ov; bidx = oi; }
    }
    if (lane == (bidx & 63)) removed |= 1u << (bidx >> 6);
    if (lane == r) tidx = bidx;
  }
  float srow[12];
#pragma unroll
  for (int r = 0; r < 12; ++r) {
    int tr = __shfl(tidx, r, 64);
    srow[r] = (lane < 32) ? S[((size_t)a * TSEQ + tr) * 32 + lane] : 0.f;
  }
  float m = 0.f;
  unsigned blocked = 0;
#pragma unroll
  for (int g = 0; g < 4; ++g) {
    float gains[12];
#pragma unroll
    for (int r = 0; r < 12; ++r) {
      float gr = (lane < 32) ? fmaxf(srow[r] - m, 0.f) : 0.f;
      gains[r] = wsum(gr);
    }
    float best = -1e30f; int bj = 0;
#pragma unroll
    for (int r = 0; r < 12; ++r) {
      float vv = ((blocked >> r) & 1u) ? -1e9f : gains[r];
      if (vv > best) { best = vv; bj = r; }
    }
    blocked |= 1u << bj;
#pragma unroll
    for (int r = 0; r < 12; ++r) m = (r == bj) ? fmaxf(m, srow[r]) : m;
    int gidx = __shfl(tidx, bj, 64);
    if (lane == 0) glob[a * 4 + g] = gidx;
  }
}

// -------- final 10-candidate attention; emits (h,m) bf16 split directly -----
__global__ __launch_bounds__(256) void attend_kernel(
    const float* __restrict__ q, const float* __restrict__ k,
    const float* __restrict__ v, const int* __restrict__ sel,
    const int* __restrict__ glob, ushort* __restrict__ Ph,
    ushort* __restrict__ Pm) {
  int wid = blockIdx.x * 4 + (threadIdx.x >> 6);
  int lane = threadIdx.x & 63;
  int bh = wid >> 11, t = wid & (TSEQ - 1);
  int h = bh % NH, b = bh / NH;
  float qv = q[((size_t)bh * TSEQ + t) * HD + lane];
  int cand[10];
  const int* selp = sel + ((size_t)bh * TSEQ + t) * 6;
#pragma unroll
  for (int c = 0; c < 6; ++c) cand[c] = selp[c];
#pragma unroll
  for (int c = 0; c < 4; ++c) cand[6 + c] = glob[h * 4 + c];
  float sc[10];
#pragma unroll
  for (int c = 0; c < 10; ++c) {
    float kv = k[((size_t)bh * TSEQ + cand[c]) * HD + lane];
    sc[c] = wsum(qv * kv);
  }
  float mx = sc[0];
#pragma unroll
  for (int c = 1; c < 10; ++c) mx = fmaxf(mx, sc[c]);
  float e[10], den = 0.f;
#pragma unroll
  for (int c = 0; c < 10; ++c) { e[c] = expf(sc[c] - mx); den += e[c]; }
  float o = 0.f;
#pragma unroll
  for (int c = 0; c < 10; ++c) {
    float w = e[c] / den;
    o += w * v[((size_t)bh * TSEQ + cand[c]) * HD + lane];
  }
  size_t idx = ((size_t)b * TSEQ + t) * DM + h * HD + lane;
  ushort hb = bf16rne(o);
  float d = o - __uint_as_float((unsigned)hb << 16);
  Ph[idx] = hb;
  Pm[idx] = bf16rne(d);
}

extern "C" void kernel_launch(void* const* d_in, const int* in_sizes, int n_in,
                              void* d_out, int out_size, void* d_ws, size_t ws_size,
                              hipStream_t stream) {
  const float* x  = (const float*)d_in[0];
  const float* Wq = (const float*)d_in[1];
  const float* bq = (const float*)d_in[2];
  const float* Wk = (const float*)d_in[3];
  const float* bk = (const float*)d_in[4];
  const float* Wv = (const float*)d_in[5];
  const float* bv = (const float*)d_in[6];
  const float* Wo = (const float*)d_in[7];
  const float* bo = (const float*)d_in[8];
  float* out = (float*)d_out;

  float* ws = (float*)d_ws;
  const size_t QKV = (size_t)NBH * TSEQ * HD;  // 3145728
  float* qb = ws;
  float* kb = qb + QKV;
  float* vb = kb + QKV;
  float* slotA = vb + QKV;                     // QKV floats: Xh+Xm, later Ph+Pm
  float* Qp = slotA + QKV;
  float* S  = Qp + (size_t)NH * 32 * HD;
  float* u  = S + (size_t)NH * TSEQ * 32;
  int* sel  = (int*)(u + (size_t)NH * TSEQ);
  int* glob = sel + (size_t)NBH * TSEQ * 6;
  ushort* wsp = (ushort*)(glob + 64);          // 12 x WN ushorts = 14.16 MB
  ushort* Xl  = wsp + (size_t)12 * WN;         // QKV ushorts = 6.29 MB

  ushort* Xh = (ushort*)slotA;
  ushort* Xm = Xh + QKV;
  ushort* Ph = Xh;  // reused after last X read (qkv) — attend runs later
  ushort* Pm = Xm;

  convert_kernel<<<dim3(1536, 5), 256, 0, stream>>>(
      x, Wq, Wk, Wv, Wo, Xh, Xm, Xl, wsp);
  qkv_kernel<<<dim3(6, 32, 3), 256, 0, stream>>>(
      Xh, Xm, Xl, wsp, bq, qb, bk, kb, bv, vb);
  window_kernel<<<12288, 256, 0, stream>>>(qb, kb, sel);
  qp_kernel<<<96, 256, 0, stream>>>(qb, Qp);
  proto_score_kernel<<<dim3(512, NH), 256, 0, stream>>>(kb, Qp, S, u);
  head_select_kernel<<<NH, 64, 0, stream>>>(u, S, glob);
  attend_kernel<<<12288, 256, 0, stream>>>(qb, kb, vb, sel, glob, Ph, Pm);
  oproj_kernel<<<dim3(6, 32), 256, 0, stream>>>(Ph, Pm, wsp, bo, out);
}

// Round 10
// 276.864 us; speedup vs baseline: 1.0110x; 1.0110x over previous
//
#include <hip/hip_runtime.h>
#include <math.h>

#define TSEQ 2048
#define DM   768
#define NH   12
#define HD   64
#define NBH  24
#define WN   589824  // 768*768

typedef __attribute__((ext_vector_type(8))) short short8;
typedef __attribute__((ext_vector_type(4))) float f32x4;

#define MFMA_BF16(a, b, c) __builtin_amdgcn_mfma_f32_16x16x32_bf16(a, b, c, 0, 0, 0)

// round(linspace(0, 2047, 32)) — verified against fp32 evaluation (no .5 ties)
__constant__ int c_idxp[32] = {0,66,132,198,264,330,396,462,528,594,660,726,
  792,858,924,990,1057,1123,1189,1255,1321,1387,1453,1519,1585,1651,1717,1783,
  1849,1915,1981,2047};

// ---- DPP helpers: row(16-lane)-local rotations on the VALU pipe ----
template <int CTRL>
__device__ __forceinline__ float dppf(float x) {
  return __int_as_float(__builtin_amdgcn_mov_dpp(__float_as_int(x), CTRL, 0xF, 0xF, true));
}
template <int CTRL>
__device__ __forceinline__ int dppi(int x) {
  return __builtin_amdgcn_mov_dpp(x, CTRL, 0xF, 0xF, true);
}
__device__ __forceinline__ float wsum(float v) {
  v += dppf<0x121>(v);
  v += dppf<0x122>(v);
  v += dppf<0x124>(v);
  v += dppf<0x128>(v);
  v += __shfl_xor(v, 16, 64);
  v += __shfl_xor(v, 32, 64);
  return v;
}
__device__ __forceinline__ float wmaxr(float v) {
  v = fmaxf(v, dppf<0x121>(v));
  v = fmaxf(v, dppf<0x122>(v));
  v = fmaxf(v, dppf<0x124>(v));
  v = fmaxf(v, dppf<0x128>(v));
  v = fmaxf(v, __shfl_xor(v, 16, 64));
  v = fmaxf(v, __shfl_xor(v, 32, 64));
  return v;
}

__device__ __forceinline__ ushort bf16rne(float x) {
  unsigned u = __float_as_uint(x);
  return (ushort)((u + 0x7fffu + ((u >> 16) & 1u)) >> 16);
}

// split 8 fp32 -> bf16 h/m/l (RNE each stage; subtractions exact)
template <bool NEED_L>
__device__ __forceinline__ void split_store(const float4& v0, const float4& v1,
                                            ushort* ph, ushort* pm, ushort* pl) {
  float xs[8] = {v0.x, v0.y, v0.z, v0.w, v1.x, v1.y, v1.z, v1.w};
  short8 h, m, l;
#pragma unroll
  for (int j = 0; j < 8; ++j) {
    float x = xs[j];
    ushort hb = bf16rne(x);
    h[j] = (short)hb;
    float d = x - __uint_as_float((unsigned)hb << 16);
    ushort mb = bf16rne(d);
    m[j] = (short)mb;
    if (NEED_L) {
      float d2 = d - __uint_as_float((unsigned)mb << 16);
      l[j] = (short)bf16rne(d2);
    }
  }
  *(short8*)ph = h;
  *(short8*)pm = m;
  if (NEED_L) *(short8*)pl = l;
}

// Swizzled LDS layout: tile stored as 128B lines (64 ushort) of 8 x 16B chunks,
// chunk' = chunk8 ^ (line&7). Conflict-free for staging writes and
// 16-lane x b128 fragment reads (one lane per bank-quad per line).
__device__ __forceinline__ int lds_idx(int row, int chunk /*0..3*/) {
  int line = row >> 1;
  int c8 = ((row & 1) << 2) | chunk;
  return line * 64 + ((c8 ^ (line & 7)) << 3);
}

// -------- pre-split: z=0 X -> Xh/Xm/Xl, z=1..4 W -> wsp[mi][lvl][WN] --------
__global__ __launch_bounds__(256) void convert_kernel(
    const float* __restrict__ x,
    const float* __restrict__ W0, const float* __restrict__ W1,
    const float* __restrict__ W2, const float* __restrict__ W3,
    ushort* __restrict__ Xh, ushort* __restrict__ Xm, ushort* __restrict__ Xl,
    ushort* __restrict__ wsp) {
  int z = blockIdx.y;
  size_t base = (size_t)(blockIdx.x * 256 + threadIdx.x) * 8;
  if (z == 0) {
    float4 v0 = *(const float4*)(x + base);
    float4 v1 = *(const float4*)(x + base + 4);
    split_store<true>(v0, v1, Xh + base, Xm + base, Xl + base);
  } else {
    if (base >= WN) return;
    int mi = z - 1;
    const float* s = (mi == 0) ? W0 : (mi == 1) ? W1 : (mi == 2) ? W2 : W3;
    ushort* h = wsp + (size_t)mi * 3 * WN;
    float4 v0 = *(const float4*)(s + base);
    float4 v1 = *(const float4*)(s + base + 4);
    split_store<true>(v0, v1, h + base, h + WN + base, h + 2 * WN + base);
  }
}

// ---------------- split-bf16 MFMA GEMM: dst = (A @ B^T + bias) * scale ------
// A and B both pre-split bf16 h/m/l in global (staging = pure short8 copies).
// 128x64 tile, BK=32, 256 thr = 4 waves (2Mx2N), per wave 4x2 16x16x32 frags.
// Product order per acc element: hh,mh,hm(,mm,lh,hl) — bit-identical to R8.
template <int MODE, int NPROD>
__device__ __forceinline__ void gemm_mfma_body(
    const ushort* __restrict__ Agh, const ushort* __restrict__ Agm,
    const ushort* __restrict__ Agl,
    const ushort* __restrict__ Bgh, const ushort* __restrict__ Bgm,
    const ushort* __restrict__ Bgl,
    const float* __restrict__ bias, float* __restrict__ dst, float scale,
    int mblk, int nblk, ushort* lds) {
  const int tid = threadIdx.x;
  const int lane = tid & 63;
  const int w = tid >> 6;
  const int wr = w >> 1, wc = w & 1;
  const int lrow = lane & 15, kq = lane >> 4;
  constexpr int ABUF = 4096;  // 128 rows x 32 ushort (64 lines x 64)
  constexpr int BBUF = 2048;  // 64 rows x 32 ushort
  ushort* Ahs = lds;
  ushort* Ams = Ahs + ABUF;
  ushort* Als = (NPROD == 6) ? (Ams + ABUF) : nullptr;
  ushort* Bhs = (NPROD == 6) ? (lds + 3 * ABUF) : (lds + 2 * ABUF);
  ushort* Bms = Bhs + BBUF;
  ushort* Bls = (NPROD == 6) ? (Bms + BBUF) : nullptr;

  const int arow = tid >> 2;   // 0..63 (and +64 for 2nd A segment)
  const int achk = tid & 3;
  const int aoff0 = lds_idx(arow, achk);
  const int aoff1 = lds_idx(arow + 64, achk);
  const int boff = lds_idx(arow, achk);

  const size_t a0 = (size_t)(mblk + arow) * DM + achk * 8;
  const size_t a1 = (size_t)(mblk + 64 + arow) * DM + achk * 8;
  const size_t b0 = (size_t)(nblk + arow) * DM + achk * 8;

  f32x4 acc[4][2];
#pragma unroll
  for (int i = 0; i < 4; ++i)
#pragma unroll
    for (int j = 0; j < 2; ++j) {
      f32x4 z = {0.f, 0.f, 0.f, 0.f};
      acc[i][j] = z;
    }

  short8 pah0 = *(const short8*)(Agh + a0), pah1 = *(const short8*)(Agh + a1);
  short8 pam0 = *(const short8*)(Agm + a0), pam1 = *(const short8*)(Agm + a1);
  short8 pal0, pal1;
  if (NPROD == 6) { pal0 = *(const short8*)(Agl + a0); pal1 = *(const short8*)(Agl + a1); }
  short8 pbh = *(const short8*)(Bgh + b0);
  short8 pbm = *(const short8*)(Bgm + b0);
  short8 pbl;
  if (NPROD == 6) pbl = *(const short8*)(Bgl + b0);

  for (int k0 = 0; k0 < DM; k0 += 32) {
    __syncthreads();
    *(short8*)&Ahs[aoff0] = pah0; *(short8*)&Ahs[aoff1] = pah1;
    *(short8*)&Ams[aoff0] = pam0; *(short8*)&Ams[aoff1] = pam1;
    if (NPROD == 6) { *(short8*)&Als[aoff0] = pal0; *(short8*)&Als[aoff1] = pal1; }
    *(short8*)&Bhs[boff] = pbh;
    *(short8*)&Bms[boff] = pbm;
    if (NPROD == 6) *(short8*)&Bls[boff] = pbl;
    __syncthreads();
    if (k0 + 32 < DM) {  // prefetch next K-tile; overlaps MFMA
      pah0 = *(const short8*)(Agh + a0 + k0 + 32);
      pah1 = *(const short8*)(Agh + a1 + k0 + 32);
      pam0 = *(const short8*)(Agm + a0 + k0 + 32);
      pam1 = *(const short8*)(Agm + a1 + k0 + 32);
      if (NPROD == 6) {
        pal0 = *(const short8*)(Agl + a0 + k0 + 32);
        pal1 = *(const short8*)(Agl + a1 + k0 + 32);
      }
      pbh = *(const short8*)(Bgh + b0 + k0 + 32);
      pbm = *(const short8*)(Bgm + b0 + k0 + 32);
      if (NPROD == 6) pbl = *(const short8*)(Bgl + b0 + k0 + 32);
    }
    short8 afh[4], afm[4], afl[4];
#pragma unroll
    for (int fi = 0; fi < 4; ++fi) {
      int o = lds_idx(wr * 64 + fi * 16 + lrow, kq);
      afh[fi] = *(const short8*)&Ahs[o];
      afm[fi] = *(const short8*)&Ams[o];
      if (NPROD == 6) afl[fi] = *(const short8*)&Als[o];
    }
#pragma unroll
    for (int fj = 0; fj < 2; ++fj) {
      int o = lds_idx(wc * 32 + fj * 16 + lrow, kq);
      short8 bfh = *(const short8*)&Bhs[o];
      short8 bfm = *(const short8*)&Bms[o];
      short8 bfl;
      if (NPROD == 6) bfl = *(const short8*)&Bls[o];
#pragma unroll
      for (int fi = 0; fi < 4; ++fi) {
        acc[fi][fj] = MFMA_BF16(afh[fi], bfh, acc[fi][fj]);
        acc[fi][fj] = MFMA_BF16(afm[fi], bfh, acc[fi][fj]);
        acc[fi][fj] = MFMA_BF16(afh[fi], bfm, acc[fi][fj]);
        if (NPROD == 6) {
          acc[fi][fj] = MFMA_BF16(afm[fi], bfm, acc[fi][fj]);
          acc[fi][fj] = MFMA_BF16(afl[fi], bfh, acc[fi][fj]);
          acc[fi][fj] = MFMA_BF16(afh[fi], bfl, acc[fi][fj]);
        }
      }
    }
  }

#pragma unroll
  for (int fj = 0; fj < 2; ++fj) {
    int col = nblk + wc * 32 + fj * 16 + lrow;
    float bv = bias[col];
#pragma unroll
    for (int fi = 0; fi < 4; ++fi) {
#pragma unroll
      for (int reg = 0; reg < 4; ++reg) {
        int row = mblk + wr * 64 + fi * 16 + kq * 4 + reg;
        float o = (acc[fi][fj][reg] + bv) * scale;
        if (MODE == 0) {
          dst[(size_t)row * DM + col] = o;
        } else {
          int b_ = row >> 11, t = row & (TSEQ - 1);
          int h = col >> 6, dd = col & 63;
          dst[(((size_t)(b_ * NH + h)) * TSEQ + t) * HD + dd] = o;
        }
      }
    }
  }
}

// merged q/k/v projection, BN=64, XCD-swizzled.
// z = 0 (q), 1 (k) NPROD6; 2 (v) NPROD3. 1152 blocks, 144 per XCD.
__global__ __launch_bounds__(256) void qkv_kernel(
    const ushort* __restrict__ Xh, const ushort* __restrict__ Xm,
    const ushort* __restrict__ Xl, const ushort* __restrict__ wsp,
    const float* __restrict__ bq, float* __restrict__ qd,
    const float* __restrict__ bk, float* __restrict__ kd,
    const float* __restrict__ bv, float* __restrict__ vd) {
  __shared__ ushort lds[3 * 4096 + 3 * 2048];  // 36 KB
  int lid = blockIdx.x + 12 * blockIdx.y + 384 * blockIdx.z;
  int swz = (lid & 7) * 144 + (lid >> 3);   // bijective: 1152 % 8 == 0
  int z = swz / 384;
  int rem = swz - z * 384;
  int wy = rem / 12, wx = rem - wy * 12;
  const ushort* Bb = wsp + (size_t)z * 3 * WN;
  if (z == 2) {
    gemm_mfma_body<1, 3>(Xh, Xm, nullptr, Bb, Bb + WN, nullptr,
                         bv, vd, 1.0f, wy * 128, wx * 64, lds);
  } else {
    gemm_mfma_body<1, 6>(Xh, Xm, Xl, Bb, Bb + WN, Bb + 2 * WN,
                         z ? bk : bq, z ? kd : qd, z ? 1.0f : 0.125f,
                         wy * 128, wx * 64, lds);
  }
}

__global__ __launch_bounds__(256) void oproj_kernel(
    const ushort* __restrict__ Ph, const ushort* __restrict__ Pm,
    const ushort* __restrict__ wsp,
    const float* __restrict__ bias, float* __restrict__ dst) {
  __shared__ ushort lds[2 * 4096 + 2 * 2048];  // 24 KB
  int lid = blockIdx.x + 12 * blockIdx.y;
  int swz = (lid & 7) * 48 + (lid >> 3);    // bijective: 384 % 8 == 0
  int wy = swz / 12, wx = swz - wy * 12;
  const ushort* Bb = wsp + (size_t)3 * 3 * WN;
  gemm_mfma_body<0, 3>(Ph, Pm, nullptr, Bb, Bb + WN, nullptr,
                       bias, dst, 1.0f, wy * 128, wx * 64, lds);
}

// ---------------- window selection: one wave per (bh, t) ----------------
__global__ __launch_bounds__(256) void window_kernel(
    const float* __restrict__ q, const float* __restrict__ k,
    int* __restrict__ sel) {
  int wid = blockIdx.x * 4 + (threadIdx.x >> 6);
  int lane = threadIdx.x & 63;
  int f = lane & 15, kq = lane >> 4;
  int bh = wid >> 11, t = wid & (TSEQ - 1);
  int start = t - 8;
  if (start < 0) start = 0;
  if (start > TSEQ - 16) start = TSEQ - 16;

  const float* kp = k + ((size_t)bh * TSEQ + start + f) * HD + kq * 8;
  const float* qp = q + ((size_t)bh * TSEQ + t) * HD + kq * 8;
  float kv[16], qv[16];
  *(float4*)&kv[0]  = *(const float4*)(kp + 0);
  *(float4*)&kv[4]  = *(const float4*)(kp + 4);
  *(float4*)&kv[8]  = *(const float4*)(kp + 32);
  *(float4*)&kv[12] = *(const float4*)(kp + 36);
  *(float4*)&qv[0]  = *(const float4*)(qp + 0);
  *(float4*)&qv[4]  = *(const float4*)(qp + 4);
  *(float4*)&qv[8]  = *(const float4*)(qp + 32);
  *(float4*)&qv[12] = *(const float4*)(qp + 36);

  float sp = 0.f, np = 0.f;
#pragma unroll
  for (int i = 0; i < 16; ++i) { sp = fmaf(qv[i], kv[i], sp); np = fmaf(kv[i], kv[i], np); }
  sp += __shfl_xor(sp, 16, 64); sp += __shfl_xor(sp, 32, 64);
  np += __shfl_xor(np, 16, 64); np += __shfl_xor(np, 32, 64);
  float nrm = fmaxf(sqrtf(np), 1e-6f);
  float kn[16];
#pragma unroll
  for (int i = 0; i < 16; ++i) kn[i] = kv[i] / nrm;

  short8 h0, m0, l0, h1, m1, l1;
#pragma unroll
  for (int j = 0; j < 8; ++j) {
    float x = kn[j];
    ushort hb = bf16rne(x); h0[j] = (short)hb;
    float d = x - __uint_as_float((unsigned)hb << 16);
    ushort mb = bf16rne(d); m0[j] = (short)mb;
    l0[j] = (short)bf16rne(d - __uint_as_float((unsigned)mb << 16));
    x = kn[8 + j];
    hb = bf16rne(x); h1[j] = (short)hb;
    d = x - __uint_as_float((unsigned)hb << 16);
    mb = bf16rne(d); m1[j] = (short)mb;
    l1[j] = (short)bf16rne(d - __uint_as_float((unsigned)mb << 16));
  }
  f32x4 g = {0.f, 0.f, 0.f, 0.f};
  g = MFMA_BF16(h0, h0, g); g = MFMA_BF16(h1, h1, g);
  g = MFMA_BF16(m0, h0, g); g = MFMA_BF16(m1, h1, g);
  g = MFMA_BF16(h0, m0, g); g = MFMA_BF16(h1, m1, g);
  g = MFMA_BF16(m0, m0, g); g = MFMA_BF16(m1, m1, g);
  g = MFMA_BF16(l0, h0, g); g = MFMA_BF16(l1, h1, g);
  g = MFMA_BF16(h0, l0, g); g = MFMA_BF16(h1, l1, g);

  int dist = start + f - t; if (dist < 0) dist = -dist;
  float tmp = sp + 0.2f * expf(-(float)dist * 0.125f);

  int* selp = sel + ((size_t)bh * TSEQ + t) * 6;
#pragma unroll
  for (int r = 0; r < 6; ++r) {
    float best = tmp; int bj = f;
    {
      float ov = dppf<0x121>(best); int oi = dppi<0x121>(bj);
      if (ov > best || (ov == best && oi < bj)) { best = ov; bj = oi; }
      ov = dppf<0x122>(best); oi = dppi<0x122>(bj);
      if (ov > best || (ov == best && oi < bj)) { best = ov; bj = oi; }
      ov = dppf<0x124>(best); oi = dppi<0x124>(bj);
      if (ov > best || (ov == best && oi < bj)) { best = ov; bj = oi; }
      ov = dppf<0x128>(best); oi = dppi<0x128>(bj);
      if (ov > best || (ov == best && oi < bj)) { best = ov; bj = oi; }
    }
    if (lane == 0) selp[r] = start + bj;
    if (r < 5) {
      float s01 = (bj & 1) ? g[1] : g[0];
      float s23 = (bj & 1) ? g[3] : g[2];
      float gsel = (bj & 2) ? s23 : s01;
      float grow = __shfl(gsel, ((bj >> 2) << 4) | f, 64);
      tmp -= 0.2f * fmaxf(grow, 0.f);
    }
    if (f == bj) tmp = -1e9f;
  }
}

// ---------------- prototype queries Qp[a][p][:] ----------------
__global__ __launch_bounds__(256) void qp_kernel(const float* __restrict__ q,
                                                 float* __restrict__ Qp) {
  int wid = blockIdx.x * 4 + (threadIdx.x >> 6);
  int lane = threadIdx.x & 63;
  int a = wid >> 5, p = wid & 31;
  int t = c_idxp[p];
  float v = 0.5f * (q[((size_t)(2 * a) * TSEQ + t) * HD + lane] +
                    q[((size_t)(2 * a + 1) * TSEQ + t) * HD + lane]);
  float n2 = wsum(v * v);
  float nrm = fmaxf(sqrtf(n2), 1e-6f);
  Qp[((size_t)a * 32 + p) * HD + lane] = v / nrm;
}

// ---------------- S[a][t][p] and u[a][t] ----------------
__global__ __launch_bounds__(256) void proto_score_kernel(
    const float* __restrict__ k, const float* __restrict__ Qp,
    float* __restrict__ S, float* __restrict__ u) {
  int a = blockIdx.y;
  __shared__ float Qs[2048];
  for (int i = threadIdx.x; i < 2048; i += 256) Qs[i] = Qp[(size_t)a * 2048 + i];
  __syncthreads();
  int w = threadIdx.x >> 6, lane = threadIdx.x & 63;
  int t = blockIdx.x * 4 + w;
  float km = 0.5f * (k[((size_t)(2 * a) * TSEQ + t) * HD + lane] +
                     k[((size_t)(2 * a + 1) * TSEQ + t) * HD + lane]);
  float n2 = wsum(km * km);
  float nrm = fmaxf(sqrtf(n2), 1e-6f);
  float kb = km / nrm;
  float sval = 0.f;
#pragma unroll
  for (int p = 0; p < 32; ++p) {
    float dg = wsum(kb * Qs[p * 64 + lane]);
    dg = fmaxf(dg, 0.f);
    sval = (lane == p) ? dg : sval;
  }
  if (lane < 32) S[((size_t)a * TSEQ + t) * 32 + lane] = sval;
  float x = (lane < 32) ? sval : 0.f;
  float mean = wsum(x) / 32.0f;
  float mx = wmaxr((lane < 32) ? sval : -1e30f);
  float cur = (lane < 32) ? sval : -1e30f;
  float topsum = 0.f;
#pragma unroll
  for (int r = 0; r < 6; ++r) {
    float m = wmaxr(cur);
    topsum += m;
    unsigned long long ball = __ballot(cur == m);
    int first = __ffsll(ball) - 1;
    if (lane == first) cur = -1e30f;
  }
  float dev = (lane < 32) ? (sval - mean) : 0.f;
  float sd = sqrtf(wsum(dev * dev) / 31.0f);
  float uval = ((1.0f * mean + 0.6f * mx) + 0.4f * (topsum / 6.0f)) + 0.2f * sd;
  if (lane == 0) u[(size_t)a * TSEQ + t] = uval;
}

// ---------------- per-head top-12 + greedy facility location ----------------
__global__ void head_select_kernel(const float* __restrict__ u,
                                   const float* __restrict__ S,
                                   int* __restrict__ glob) {
  int a = blockIdx.x;
  int lane = threadIdx.x;
  float uv[32];
#pragma unroll
  for (int c = 0; c < 32; ++c) uv[c] = u[(size_t)a * TSEQ + c * 64 + lane];
  unsigned removed = 0;
  int tidx = 0;
#pragma unroll
  for (int r = 0; r < 12; ++r) {
    float best = -1e30f; int bidx = 1 << 30;
#pragma unroll
    for (int c = 0; c < 32; ++c) {
      if (!((removed >> c) & 1u)) {
        float vv = uv[c]; int gi = c * 64 + lane;
        if (vv > best || (vv == best && gi < bidx)) { best = vv; bidx = gi; }
      }
    }
#pragma unroll
    for (int mS = 1; mS < 64; mS <<= 1) {
      float ov = __shfl_xor(best, mS, 64);
      int oi = __shfl_xor(bidx, mS, 64);
      if (ov > best || (ov == best && oi < bidx)) { best = ov; bidx = oi; }
    }
    if (lane == (bidx & 63)) removed |= 1u << (bidx >> 6);
    if (lane == r) tidx = bidx;
  }
  float srow[12];
#pragma unroll
  for (int r = 0; r < 12; ++r) {
    int tr = __shfl(tidx, r, 64);
    srow[r] = (lane < 32) ? S[((size_t)a * TSEQ + tr) * 32 + lane] : 0.f;
  }
  float m = 0.f;
  unsigned blocked = 0;
#pragma unroll
  for (int g = 0; g < 4; ++g) {
    float gains[12];
#pragma unroll
    for (int r = 0; r < 12; ++r) {
      float gr = (lane < 32) ? fmaxf(srow[r] - m, 0.f) : 0.f;
      gains[r] = wsum(gr);
    }
    float best = -1e30f; int bj = 0;
#pragma unroll
    for (int r = 0; r < 12; ++r) {
      float vv = ((blocked >> r) & 1u) ? -1e9f : gains[r];
      if (vv > best) { best = vv; bj = r; }
    }
    blocked |= 1u << bj;
#pragma unroll
    for (int r = 0; r < 12; ++r) m = (r == bj) ? fmaxf(m, srow[r]) : m;
    int gidx = __shfl(tidx, bj, 64);
    if (lane == 0) glob[a * 4 + g] = gidx;
  }
}

// -------- final 10-candidate attention; emits (h,m) bf16 split directly -----
__global__ __launch_bounds__(256) void attend_kernel(
    const float* __restrict__ q, const float* __restrict__ k,
    const float* __restrict__ v, const int* __restrict__ sel,
    const int* __restrict__ glob, ushort* __restrict__ Ph,
    ushort* __restrict__ Pm) {
  int wid = blockIdx.x * 4 + (threadIdx.x >> 6);
  int lane = threadIdx.x & 63;
  int bh = wid >> 11, t = wid & (TSEQ - 1);
  int h = bh % NH, b = bh / NH;
  float qv = q[((size_t)bh * TSEQ + t) * HD + lane];
  int cand[10];
  const int* selp = sel + ((size_t)bh * TSEQ + t) * 6;
#pragma unroll
  for (int c = 0; c < 6; ++c) cand[c] = selp[c];
#pragma unroll
  for (int c = 0; c < 4; ++c) cand[6 + c] = glob[h * 4 + c];
  float sc[10];
#pragma unroll
  for (int c = 0; c < 10; ++c) {
    float kv = k[((size_t)bh * TSEQ + cand[c]) * HD + lane];
    sc[c] = wsum(qv * kv);
  }
  float mx = sc[0];
#pragma unroll
  for (int c = 1; c < 10; ++c) mx = fmaxf(mx, sc[c]);
  float e[10], den = 0.f;
#pragma unroll
  for (int c = 0; c < 10; ++c) { e[c] = expf(sc[c] - mx); den += e[c]; }
  float o = 0.f;
#pragma unroll
  for (int c = 0; c < 10; ++c) {
    float w = e[c] / den;
    o += w * v[((size_t)bh * TSEQ + cand[c]) * HD + lane];
  }
  size_t idx = ((size_t)b * TSEQ + t) * DM + h * HD + lane;
  ushort hb = bf16rne(o);
  float d = o - __uint_as_float((unsigned)hb << 16);
  Ph[idx] = hb;
  Pm[idx] = bf16rne(d);
}

extern "C" void kernel_launch(void* const* d_in, const int* in_sizes, int n_in,
                              void* d_out, int out_size, void* d_ws, size_t ws_size,
                              hipStream_t stream) {
  const float* x  = (const float*)d_in[0];
  const float* Wq = (const float*)d_in[1];
  const float* bq = (const float*)d_in[2];
  const float* Wk = (const float*)d_in[3];
  const float* bk = (const float*)d_in[4];
  const float* Wv = (const float*)d_in[5];
  const float* bv = (const float*)d_in[6];
  const float* Wo = (const float*)d_in[7];
  const float* bo = (const float*)d_in[8];
  float* out = (float*)d_out;

  float* ws = (float*)d_ws;
  const size_t QKV = (size_t)NBH * TSEQ * HD;  // 3145728
  float* qb = ws;
  float* kb = qb + QKV;
  float* vb = kb + QKV;
  float* slotA = vb + QKV;                     // QKV floats: Xh+Xm, later Ph+Pm
  float* Qp = slotA + QKV;
  float* S  = Qp + (size_t)NH * 32 * HD;
  float* u  = S + (size_t)NH * TSEQ * 32;
  int* sel  = (int*)(u + (size_t)NH * TSEQ);
  int* glob = sel + (size_t)NBH * TSEQ * 6;
  ushort* wsp = (ushort*)(glob + 64);          // 12 x WN ushorts = 14.16 MB
  ushort* Xl  = wsp + (size_t)12 * WN;         // QKV ushorts = 6.29 MB

  ushort* Xh = (ushort*)slotA;
  ushort* Xm = Xh + QKV;
  ushort* Ph = Xh;  // reused after last X read (qkv) — attend runs later
  ushort* Pm = Xm;

  convert_kernel<<<dim3(1536, 5), 256, 0, stream>>>(
      x, Wq, Wk, Wv, Wo, Xh, Xm, Xl, wsp);
  qkv_kernel<<<dim3(12, 32, 3), 256, 0, stream>>>(
      Xh, Xm, Xl, wsp, bq, qb, bk, kb, bv, vb);
  window_kernel<<<12288, 256, 0, stream>>>(qb, kb, sel);
  qp_kernel<<<96, 256, 0, stream>>>(qb, Qp);
  proto_score_kernel<<<dim3(512, NH), 256, 0, stream>>>(kb, Qp, S, u);
  head_select_kernel<<<NH, 64, 0, stream>>>(u, S, glob);
  attend_kernel<<<12288, 256, 0, stream>>>(qb, kb, vb, sel, glob, Ph, Pm);
  oproj_kernel<<<dim3(12, 32), 256, 0, stream>>>(Ph, Pm, wsp, bo, out);
}

// Round 11
// 243.638 us; speedup vs baseline: 1.1488x; 1.1364x over previous
//
#include <hip/hip_runtime.h>
#include <math.h>

#define TSEQ 2048
#define DM   768
#define NH   12
#define HD   64
#define NBH  24
#define WN   589824  // 768*768

typedef __attribute__((ext_vector_type(8))) short short8;
typedef __attribute__((ext_vector_type(8))) _Float16 half8;
typedef __attribute__((ext_vector_type(4))) float f32x4;

#define MFMA_BF16(a, b, c) __builtin_amdgcn_mfma_f32_16x16x32_bf16(a, b, c, 0, 0, 0)
#define MFMA_F16(a, b, c)  __builtin_amdgcn_mfma_f32_16x16x32_f16(a, b, c, 0, 0, 0)

// round(linspace(0, 2047, 32)) — verified against fp32 evaluation (no .5 ties)
__constant__ int c_idxp[32] = {0,66,132,198,264,330,396,462,528,594,660,726,
  792,858,924,990,1057,1123,1189,1255,1321,1387,1453,1519,1585,1651,1717,1783,
  1849,1915,1981,2047};

// ---- DPP helpers: row(16-lane)-local rotations on the VALU pipe ----
template <int CTRL>
__device__ __forceinline__ float dppf(float x) {
  return __int_as_float(__builtin_amdgcn_mov_dpp(__float_as_int(x), CTRL, 0xF, 0xF, true));
}
template <int CTRL>
__device__ __forceinline__ int dppi(int x) {
  return __builtin_amdgcn_mov_dpp(x, CTRL, 0xF, 0xF, true);
}
__device__ __forceinline__ float wsum(float v) {
  v += dppf<0x121>(v);
  v += dppf<0x122>(v);
  v += dppf<0x124>(v);
  v += dppf<0x128>(v);
  v += __shfl_xor(v, 16, 64);
  v += __shfl_xor(v, 32, 64);
  return v;
}
__device__ __forceinline__ float wmaxr(float v) {
  v = fmaxf(v, dppf<0x121>(v));
  v = fmaxf(v, dppf<0x122>(v));
  v = fmaxf(v, dppf<0x124>(v));
  v = fmaxf(v, dppf<0x128>(v));
  v = fmaxf(v, __shfl_xor(v, 16, 64));
  v = fmaxf(v, __shfl_xor(v, 32, 64));
  return v;
}

__device__ __forceinline__ ushort bf16rne(float x) {
  unsigned u = __float_as_uint(x);
  return (ushort)((u + 0x7fffu + ((u >> 16) & 1u)) >> 16);
}

// split 8 fp32 -> fp16 h/l (RNE both; h+l captures ~22 significand bits)
__device__ __forceinline__ void split16(const float4& v0, const float4& v1,
                                        ushort* ph, ushort* pl) {
  float xs[8] = {v0.x, v0.y, v0.z, v0.w, v1.x, v1.y, v1.z, v1.w};
  half8 h, l;
#pragma unroll
  for (int j = 0; j < 8; ++j) {
    _Float16 hb = (_Float16)xs[j];
    h[j] = hb;
    float d = xs[j] - (float)hb;
    l[j] = (_Float16)d;
  }
  *(half8*)ph = h;
  *(half8*)pl = l;
}

// Swizzled LDS layout: tile stored as 128B lines (64 ushort) of 8 x 16B chunks,
// chunk' = chunk8 ^ (line&7). Conflict-free for staging writes and
// 16-lane x b128 fragment reads (one lane per bank-quad per line).
__device__ __forceinline__ int lds_idx(int row, int chunk /*0..3*/) {
  int line = row >> 1;
  int c8 = ((row & 1) << 2) | chunk;
  return line * 64 + ((c8 ^ (line & 7)) << 3);
}

// -------- pre-split: z=0 X -> Xh/Xl, z=1..4 W -> wsp[mi][lvl][WN] -----------
__global__ __launch_bounds__(256) void convert_kernel(
    const float* __restrict__ x,
    const float* __restrict__ W0, const float* __restrict__ W1,
    const float* __restrict__ W2, const float* __restrict__ W3,
    ushort* __restrict__ Xh, ushort* __restrict__ Xl,
    ushort* __restrict__ wsp) {
  int z = blockIdx.y;
  size_t base = (size_t)(blockIdx.x * 256 + threadIdx.x) * 8;
  if (z == 0) {
    float4 v0 = *(const float4*)(x + base);
    float4 v1 = *(const float4*)(x + base + 4);
    split16(v0, v1, Xh + base, Xl + base);
  } else {
    if (base >= WN) return;
    int mi = z - 1;
    const float* s = (mi == 0) ? W0 : (mi == 1) ? W1 : (mi == 2) ? W2 : W3;
    ushort* h = wsp + (size_t)mi * 2 * WN;
    float4 v0 = *(const float4*)(s + base);
    float4 v1 = *(const float4*)(s + base + 4);
    split16(v0, v1, h + base, h + WN + base);
  }
}

// ---------------- split-fp16 MFMA GEMM: dst = (A @ B^T + bias) * scale ------
// A and B pre-split fp16 h/l in global (staging = pure short8 copies).
// 128x64 tile, BK=32, 256 thr = 4 waves (2Mx2N), per wave 4x2 16x16x32 frags.
// NPROD=4: hh+lh+hl+ll (err ~2^-22, selection-safe: below existing
// reorder-noise vs the fp32 reference). NPROD=3: hh+lh+hl (value path).
template <int MODE, int NPROD>
__device__ __forceinline__ void gemm_mfma_body(
    const ushort* __restrict__ Agh, const ushort* __restrict__ Agl,
    const ushort* __restrict__ Bgh, const ushort* __restrict__ Bgl,
    const float* __restrict__ bias, float* __restrict__ dst, float scale,
    int mblk, int nblk, ushort* lds) {
  const int tid = threadIdx.x;
  const int lane = tid & 63;
  const int w = tid >> 6;
  const int wr = w >> 1, wc = w & 1;
  const int lrow = lane & 15, kq = lane >> 4;
  constexpr int ABUF = 4096;  // 128 rows x 32 ushort (64 lines x 64)
  constexpr int BBUF = 2048;  // 64 rows x 32 ushort
  ushort* Ahs = lds;
  ushort* Als = Ahs + ABUF;
  ushort* Bhs = lds + 2 * ABUF;
  ushort* Bls = Bhs + BBUF;

  const int arow = tid >> 2;   // 0..63 (and +64 for 2nd A segment)
  const int achk = tid & 3;
  const int aoff0 = lds_idx(arow, achk);
  const int aoff1 = lds_idx(arow + 64, achk);
  const int boff = lds_idx(arow, achk);

  const size_t a0 = (size_t)(mblk + arow) * DM + achk * 8;
  const size_t a1 = (size_t)(mblk + 64 + arow) * DM + achk * 8;
  const size_t b0 = (size_t)(nblk + arow) * DM + achk * 8;

  f32x4 acc[4][2];
#pragma unroll
  for (int i = 0; i < 4; ++i)
#pragma unroll
    for (int j = 0; j < 2; ++j) {
      f32x4 z = {0.f, 0.f, 0.f, 0.f};
      acc[i][j] = z;
    }

  short8 pah0 = *(const short8*)(Agh + a0), pah1 = *(const short8*)(Agh + a1);
  short8 pal0 = *(const short8*)(Agl + a0), pal1 = *(const short8*)(Agl + a1);
  short8 pbh = *(const short8*)(Bgh + b0);
  short8 pbl = *(const short8*)(Bgl + b0);

  for (int k0 = 0; k0 < DM; k0 += 32) {
    __syncthreads();
    *(short8*)&Ahs[aoff0] = pah0; *(short8*)&Ahs[aoff1] = pah1;
    *(short8*)&Als[aoff0] = pal0; *(short8*)&Als[aoff1] = pal1;
    *(short8*)&Bhs[boff] = pbh;
    *(short8*)&Bls[boff] = pbl;
    __syncthreads();
    if (k0 + 32 < DM) {  // prefetch next K-tile; overlaps MFMA
      pah0 = *(const short8*)(Agh + a0 + k0 + 32);
      pah1 = *(const short8*)(Agh + a1 + k0 + 32);
      pal0 = *(const short8*)(Agl + a0 + k0 + 32);
      pal1 = *(const short8*)(Agl + a1 + k0 + 32);
      pbh = *(const short8*)(Bgh + b0 + k0 + 32);
      pbl = *(const short8*)(Bgl + b0 + k0 + 32);
    }
    half8 afh[4], afl[4];
#pragma unroll
    for (int fi = 0; fi < 4; ++fi) {
      int o = lds_idx(wr * 64 + fi * 16 + lrow, kq);
      afh[fi] = *(const half8*)&Ahs[o];
      afl[fi] = *(const half8*)&Als[o];
    }
#pragma unroll
    for (int fj = 0; fj < 2; ++fj) {
      int o = lds_idx(wc * 32 + fj * 16 + lrow, kq);
      half8 bfh = *(const half8*)&Bhs[o];
      half8 bfl = *(const half8*)&Bls[o];
#pragma unroll
      for (int fi = 0; fi < 4; ++fi) {
        acc[fi][fj] = MFMA_F16(afh[fi], bfh, acc[fi][fj]);
        acc[fi][fj] = MFMA_F16(afl[fi], bfh, acc[fi][fj]);
        acc[fi][fj] = MFMA_F16(afh[fi], bfl, acc[fi][fj]);
        if (NPROD == 4) {
          acc[fi][fj] = MFMA_F16(afl[fi], bfl, acc[fi][fj]);
        }
      }
    }
  }

#pragma unroll
  for (int fj = 0; fj < 2; ++fj) {
    int col = nblk + wc * 32 + fj * 16 + lrow;
    float bv = bias[col];
#pragma unroll
    for (int fi = 0; fi < 4; ++fi) {
#pragma unroll
      for (int reg = 0; reg < 4; ++reg) {
        int row = mblk + wr * 64 + fi * 16 + kq * 4 + reg;
        float o = (acc[fi][fj][reg] + bv) * scale;
        if (MODE == 0) {
          dst[(size_t)row * DM + col] = o;
        } else {
          int b_ = row >> 11, t = row & (TSEQ - 1);
          int h = col >> 6, dd = col & 63;
          dst[(((size_t)(b_ * NH + h)) * TSEQ + t) * HD + dd] = o;
        }
      }
    }
  }
}

// merged q/k/v projection, BN=64, XCD-swizzled.
// z = 0 (q), 1 (k) NPROD4; 2 (v) NPROD3. 1152 blocks, 144 per XCD.
__global__ __launch_bounds__(256) void qkv_kernel(
    const ushort* __restrict__ Xh, const ushort* __restrict__ Xl,
    const ushort* __restrict__ wsp,
    const float* __restrict__ bq, float* __restrict__ qd,
    const float* __restrict__ bk, float* __restrict__ kd,
    const float* __restrict__ bv, float* __restrict__ vd) {
  __shared__ ushort lds[2 * 4096 + 2 * 2048];  // 24 KB
  int lid = blockIdx.x + 12 * blockIdx.y + 384 * blockIdx.z;
  int swz = (lid & 7) * 144 + (lid >> 3);   // bijective: 1152 % 8 == 0
  int z = swz / 384;
  int rem = swz - z * 384;
  int wy = rem / 12, wx = rem - wy * 12;
  const ushort* Bb = wsp + (size_t)z * 2 * WN;
  if (z == 2) {
    gemm_mfma_body<1, 3>(Xh, Xl, Bb, Bb + WN,
                         bv, vd, 1.0f, wy * 128, wx * 64, lds);
  } else {
    gemm_mfma_body<1, 4>(Xh, Xl, Bb, Bb + WN,
                         z ? bk : bq, z ? kd : qd, z ? 1.0f : 0.125f,
                         wy * 128, wx * 64, lds);
  }
}

__global__ __launch_bounds__(256) void oproj_kernel(
    const ushort* __restrict__ Ph, const ushort* __restrict__ Pl,
    const ushort* __restrict__ wsp,
    const float* __restrict__ bias, float* __restrict__ dst) {
  __shared__ ushort lds[2 * 4096 + 2 * 2048];  // 24 KB
  int lid = blockIdx.x + 12 * blockIdx.y;
  int swz = (lid & 7) * 48 + (lid >> 3);    // bijective: 384 % 8 == 0
  int wy = swz / 12, wx = swz - wy * 12;
  const ushort* Bb = wsp + (size_t)3 * 2 * WN;
  gemm_mfma_body<0, 3>(Ph, Pl, Bb, Bb + WN,
                       bias, dst, 1.0f, wy * 128, wx * 64, lds);
}

// ---------------- window selection: one wave per (bh, t) ----------------
// (unchanged bf16-3way Gram path — proven selection-safe)
__global__ __launch_bounds__(256) void window_kernel(
    const float* __restrict__ q, const float* __restrict__ k,
    int* __restrict__ sel) {
  int wid = blockIdx.x * 4 + (threadIdx.x >> 6);
  int lane = threadIdx.x & 63;
  int f = lane & 15, kq = lane >> 4;
  int bh = wid >> 11, t = wid & (TSEQ - 1);
  int start = t - 8;
  if (start < 0) start = 0;
  if (start > TSEQ - 16) start = TSEQ - 16;

  const float* kp = k + ((size_t)bh * TSEQ + start + f) * HD + kq * 8;
  const float* qp = q + ((size_t)bh * TSEQ + t) * HD + kq * 8;
  float kv[16], qv[16];
  *(float4*)&kv[0]  = *(const float4*)(kp + 0);
  *(float4*)&kv[4]  = *(const float4*)(kp + 4);
  *(float4*)&kv[8]  = *(const float4*)(kp + 32);
  *(float4*)&kv[12] = *(const float4*)(kp + 36);
  *(float4*)&qv[0]  = *(const float4*)(qp + 0);
  *(float4*)&qv[4]  = *(const float4*)(qp + 4);
  *(float4*)&qv[8]  = *(const float4*)(qp + 32);
  *(float4*)&qv[12] = *(const float4*)(qp + 36);

  float sp = 0.f, np = 0.f;
#pragma unroll
  for (int i = 0; i < 16; ++i) { sp = fmaf(qv[i], kv[i], sp); np = fmaf(kv[i], kv[i], np); }
  sp += __shfl_xor(sp, 16, 64); sp += __shfl_xor(sp, 32, 64);
  np += __shfl_xor(np, 16, 64); np += __shfl_xor(np, 32, 64);
  float nrm = fmaxf(sqrtf(np), 1e-6f);
  float kn[16];
#pragma unroll
  for (int i = 0; i < 16; ++i) kn[i] = kv[i] / nrm;

  short8 h0, m0, l0, h1, m1, l1;
#pragma unroll
  for (int j = 0; j < 8; ++j) {
    float x = kn[j];
    ushort hb = bf16rne(x); h0[j] = (short)hb;
    float d = x - __uint_as_float((unsigned)hb << 16);
    ushort mb = bf16rne(d); m0[j] = (short)mb;
    l0[j] = (short)bf16rne(d - __uint_as_float((unsigned)mb << 16));
    x = kn[8 + j];
    hb = bf16rne(x); h1[j] = (short)hb;
    d = x - __uint_as_float((unsigned)hb << 16);
    mb = bf16rne(d); m1[j] = (short)mb;
    l1[j] = (short)bf16rne(d - __uint_as_float((unsigned)mb << 16));
  }
  f32x4 g = {0.f, 0.f, 0.f, 0.f};
  g = MFMA_BF16(h0, h0, g); g = MFMA_BF16(h1, h1, g);
  g = MFMA_BF16(m0, h0, g); g = MFMA_BF16(m1, h1, g);
  g = MFMA_BF16(h0, m0, g); g = MFMA_BF16(h1, m1, g);
  g = MFMA_BF16(m0, m0, g); g = MFMA_BF16(m1, m1, g);
  g = MFMA_BF16(l0, h0, g); g = MFMA_BF16(l1, h1, g);
  g = MFMA_BF16(h0, l0, g); g = MFMA_BF16(h1, l1, g);

  int dist = start + f - t; if (dist < 0) dist = -dist;
  float tmp = sp + 0.2f * expf(-(float)dist * 0.125f);

  int* selp = sel + ((size_t)bh * TSEQ + t) * 6;
#pragma unroll
  for (int r = 0; r < 6; ++r) {
    float best = tmp; int bj = f;
    {
      float ov = dppf<0x121>(best); int oi = dppi<0x121>(bj);
      if (ov > best || (ov == best && oi < bj)) { best = ov; bj = oi; }
      ov = dppf<0x122>(best); oi = dppi<0x122>(bj);
      if (ov > best || (ov == best && oi < bj)) { best = ov; bj = oi; }
      ov = dppf<0x124>(best); oi = dppi<0x124>(bj);
      if (ov > best || (ov == best && oi < bj)) { best = ov; bj = oi; }
      ov = dppf<0x128>(best); oi = dppi<0x128>(bj);
      if (ov > best || (ov == best && oi < bj)) { best = ov; bj = oi; }
    }
    if (lane == 0) selp[r] = start + bj;
    if (r < 5) {
      float s01 = (bj & 1) ? g[1] : g[0];
      float s23 = (bj & 1) ? g[3] : g[2];
      float gsel = (bj & 2) ? s23 : s01;
      float grow = __shfl(gsel, ((bj >> 2) << 4) | f, 64);
      tmp -= 0.2f * fmaxf(grow, 0.f);
    }
    if (f == bj) tmp = -1e9f;
  }
}

// ---------------- prototype queries Qp[a][p][:] ----------------
__global__ __launch_bounds__(256) void qp_kernel(const float* __restrict__ q,
                                                 float* __restrict__ Qp) {
  int wid = blockIdx.x * 4 + (threadIdx.x >> 6);
  int lane = threadIdx.x & 63;
  int a = wid >> 5, p = wid & 31;
  int t = c_idxp[p];
  float v = 0.5f * (q[((size_t)(2 * a) * TSEQ + t) * HD + lane] +
                    q[((size_t)(2 * a + 1) * TSEQ + t) * HD + lane]);
  float n2 = wsum(v * v);
  float nrm = fmaxf(sqrtf(n2), 1e-6f);
  Qp[((size_t)a * 32 + p) * HD + lane] = v / nrm;
}

// ---------------- S[a][t][p] and u[a][t] ----------------
__global__ __launch_bounds__(256) void proto_score_kernel(
    const float* __restrict__ k, const float* __restrict__ Qp,
    float* __restrict__ S, float* __restrict__ u) {
  int a = blockIdx.y;
  __shared__ float Qs[2048];
  for (int i = threadIdx.x; i < 2048; i += 256) Qs[i] = Qp[(size_t)a * 2048 + i];
  __syncthreads();
  int w = threadIdx.x >> 6, lane = threadIdx.x & 63;
  int t = blockIdx.x * 4 + w;
  float km = 0.5f * (k[((size_t)(2 * a) * TSEQ + t) * HD + lane] +
                     k[((size_t)(2 * a + 1) * TSEQ + t) * HD + lane]);
  float n2 = wsum(km * km);
  float nrm = fmaxf(sqrtf(n2), 1e-6f);
  float kb = km / nrm;
  float sval = 0.f;
#pragma unroll
  for (int p = 0; p < 32; ++p) {
    float dg = wsum(kb * Qs[p * 64 + lane]);
    dg = fmaxf(dg, 0.f);
    sval = (lane == p) ? dg : sval;
  }
  if (lane < 32) S[((size_t)a * TSEQ + t) * 32 + lane] = sval;
  float x = (lane < 32) ? sval : 0.f;
  float mean = wsum(x) / 32.0f;
  float mx = wmaxr((lane < 32) ? sval : -1e30f);
  float cur = (lane < 32) ? sval : -1e30f;
  float topsum = 0.f;
#pragma unroll
  for (int r = 0; r < 6; ++r) {
    float m = wmaxr(cur);
    topsum += m;
    unsigned long long ball = __ballot(cur == m);
    int first = __ffsll(ball) - 1;
    if (lane == first) cur = -1e30f;
  }
  float dev = (lane < 32) ? (sval - mean) : 0.f;
  float sd = sqrtf(wsum(dev * dev) / 31.0f);
  float uval = ((1.0f * mean + 0.6f * mx) + 0.4f * (topsum / 6.0f)) + 0.2f * sd;
  if (lane == 0) u[(size_t)a * TSEQ + t] = uval;
}

// ---------------- per-head top-12 + greedy facility location ----------------
__global__ void head_select_kernel(const float* __restrict__ u,
                                   const float* __restrict__ S,
                                   int* __restrict__ glob) {
  int a = blockIdx.x;
  int lane = threadIdx.x;
  float uv[32];
#pragma unroll
  for (int c = 0; c < 32; ++c) uv[c] = u[(size_t)a * TSEQ + c * 64 + lane];
  unsigned removed = 0;
  int tidx = 0;
#pragma unroll
  for (int r = 0; r < 12; ++r) {
    float best = -1e30f; int bidx = 1 << 30;
#pragma unroll
    for (int c = 0; c < 32; ++c) {
      if (!((removed >> c) & 1u)) {
        float vv = uv[c]; int gi = c * 64 + lane;
        if (vv > best || (vv == best && gi < bidx)) { best = vv; bidx = gi; }
      }
    }
#pragma unroll
    for (int mS = 1; mS < 64; mS <<= 1) {
      float ov = __shfl_xor(best, mS, 64);
      int oi = __shfl_xor(bidx, mS, 64);
      if (ov > best || (ov == best && oi < bidx)) { best = ov; bidx = oi; }
    }
    if (lane == (bidx & 63)) removed |= 1u << (bidx >> 6);
    if (lane == r) tidx = bidx;
  }
  float srow[12];
#pragma unroll
  for (int r = 0; r < 12; ++r) {
    int tr = __shfl(tidx, r, 64);
    srow[r] = (lane < 32) ? S[((size_t)a * TSEQ + tr) * 32 + lane] : 0.f;
  }
  float m = 0.f;
  unsigned blocked = 0;
#pragma unroll
  for (int g = 0; g < 4; ++g) {
    float gains[12];
#pragma unroll
    for (int r = 0; r < 12; ++r) {
      float gr = (lane < 32) ? fmaxf(srow[r] - m, 0.f) : 0.f;
      gains[r] = wsum(gr);
    }
    float best = -1e30f; int bj = 0;
#pragma unroll
    for (int r = 0; r < 12; ++r) {
      float vv = ((blocked >> r) & 1u) ? -1e9f : gains[r];
      if (vv > best) { best = vv; bj = r; }
    }
    blocked |= 1u << bj;
#pragma unroll
    for (int r = 0; r < 12; ++r) m = (r == bj) ? fmaxf(m, srow[r]) : m;
    int gidx = __shfl(tidx, bj, 64);
    if (lane == 0) glob[a * 4 + g] = gidx;
  }
}

// -------- final 10-candidate attention; emits (h,l) fp16 split directly -----
__global__ __launch_bounds__(256) void attend_kernel(
    const float* __restrict__ q, const float* __restrict__ k,
    const float* __restrict__ v, const int* __restrict__ sel,
    const int* __restrict__ glob, ushort* __restrict__ Ph,
    ushort* __restrict__ Pl) {
  int wid = blockIdx.x * 4 + (threadIdx.x >> 6);
  int lane = threadIdx.x & 63;
  int bh = wid >> 11, t = wid & (TSEQ - 1);
  int h = bh % NH, b = bh / NH;
  float qv = q[((size_t)bh * TSEQ + t) * HD + lane];
  int cand[10];
  const int* selp = sel + ((size_t)bh * TSEQ + t) * 6;
#pragma unroll
  for (int c = 0; c < 6; ++c) cand[c] = selp[c];
#pragma unroll
  for (int c = 0; c < 4; ++c) cand[6 + c] = glob[h * 4 + c];
  float sc[10];
#pragma unroll
  for (int c = 0; c < 10; ++c) {
    float kv = k[((size_t)bh * TSEQ + cand[c]) * HD + lane];
    sc[c] = wsum(qv * kv);
  }
  float mx = sc[0];
#pragma unroll
  for (int c = 1; c < 10; ++c) mx = fmaxf(mx, sc[c]);
  float e[10], den = 0.f;
#pragma unroll
  for (int c = 0; c < 10; ++c) { e[c] = expf(sc[c] - mx); den += e[c]; }
  float o = 0.f;
#pragma unroll
  for (int c = 0; c < 10; ++c) {
    float w = e[c] / den;
    o += w * v[((size_t)bh * TSEQ + cand[c]) * HD + lane];
  }
  size_t idx = ((size_t)b * TSEQ + t) * DM + h * HD + lane;
  _Float16 hb = (_Float16)o;
  float d = o - (float)hb;
  Ph[idx] = __builtin_bit_cast(ushort, hb);
  _Float16 lb = (_Float16)d;
  Pl[idx] = __builtin_bit_cast(ushort, lb);
}

extern "C" void kernel_launch(void* const* d_in, const int* in_sizes, int n_in,
                              void* d_out, int out_size, void* d_ws, size_t ws_size,
                              hipStream_t stream) {
  const float* x  = (const float*)d_in[0];
  const float* Wq = (const float*)d_in[1];
  const float* bq = (const float*)d_in[2];
  const float* Wk = (const float*)d_in[3];
  const float* bk = (const float*)d_in[4];
  const float* Wv = (const float*)d_in[5];
  const float* bv = (const float*)d_in[6];
  const float* Wo = (const float*)d_in[7];
  const float* bo = (const float*)d_in[8];
  float* out = (float*)d_out;

  float* ws = (float*)d_ws;
  const size_t QKV = (size_t)NBH * TSEQ * HD;  // 3145728
  float* qb = ws;
  float* kb = qb + QKV;
  float* vb = kb + QKV;
  float* slotA = vb + QKV;                     // QKV floats: Xh+Xl, later Ph+Pl
  float* Qp = slotA + QKV;
  float* S  = Qp + (size_t)NH * 32 * HD;
  float* u  = S + (size_t)NH * TSEQ * 32;
  int* sel  = (int*)(u + (size_t)NH * TSEQ);
  int* glob = sel + (size_t)NBH * TSEQ * 6;
  ushort* wsp = (ushort*)(glob + 64);          // 8 x WN ushorts = 9.44 MB

  ushort* Xh = (ushort*)slotA;
  ushort* Xl = Xh + QKV;
  ushort* Ph = Xh;  // reused after last X read (qkv) — attend runs later
  ushort* Pl = Xl;

  convert_kernel<<<dim3(1536, 5), 256, 0, stream>>>(
      x, Wq, Wk, Wv, Wo, Xh, Xl, wsp);
  qkv_kernel<<<dim3(12, 32, 3), 256, 0, stream>>>(
      Xh, Xl, wsp, bq, qb, bk, kb, bv, vb);
  window_kernel<<<12288, 256, 0, stream>>>(qb, kb, sel);
  qp_kernel<<<96, 256, 0, stream>>>(qb, Qp);
  proto_score_kernel<<<dim3(512, NH), 256, 0, stream>>>(kb, Qp, S, u);
  head_select_kernel<<<NH, 64, 0, stream>>>(u, S, glob);
  attend_kernel<<<12288, 256, 0, stream>>>(qb, kb, vb, sel, glob, Ph, Pl);
  oproj_kernel<<<dim3(12, 32), 256, 0, stream>>>(Ph, Pl, wsp, bo, out);
}

// Round 12
// 217.058 us; speedup vs baseline: 1.2895x; 1.1225x over previous
//
#include <hip/hip_runtime.h>
#include <math.h>

#define TSEQ 2048
#define DM   768
#define NH   12
#define HD   64
#define NBH  24
#define WN   589824  // 768*768

typedef __attribute__((ext_vector_type(8))) short short8;
typedef __attribute__((ext_vector_type(8))) _Float16 half8;
typedef __attribute__((ext_vector_type(4))) float f32x4;

#define MFMA_F16(a, b, c)  __builtin_amdgcn_mfma_f32_16x16x32_f16(a, b, c, 0, 0, 0)

// round(linspace(0, 2047, 32)) — verified against fp32 evaluation (no .5 ties)
__constant__ int c_idxp[32] = {0,66,132,198,264,330,396,462,528,594,660,726,
  792,858,924,990,1057,1123,1189,1255,1321,1387,1453,1519,1585,1651,1717,1783,
  1849,1915,1981,2047};

// ---- DPP helpers: row(16-lane)-local rotations on the VALU pipe ----
template <int CTRL>
__device__ __forceinline__ float dppf(float x) {
  return __int_as_float(__builtin_amdgcn_mov_dpp(__float_as_int(x), CTRL, 0xF, 0xF, true));
}
template <int CTRL>
__device__ __forceinline__ int dppi(int x) {
  return __builtin_amdgcn_mov_dpp(x, CTRL, 0xF, 0xF, true);
}
__device__ __forceinline__ float wsum(float v) {
  v += dppf<0x121>(v);
  v += dppf<0x122>(v);
  v += dppf<0x124>(v);
  v += dppf<0x128>(v);
  v += __shfl_xor(v, 16, 64);
  v += __shfl_xor(v, 32, 64);
  return v;
}
__device__ __forceinline__ float wmaxr(float v) {
  v = fmaxf(v, dppf<0x121>(v));
  v = fmaxf(v, dppf<0x122>(v));
  v = fmaxf(v, dppf<0x124>(v));
  v = fmaxf(v, dppf<0x128>(v));
  v = fmaxf(v, __shfl_xor(v, 16, 64));
  v = fmaxf(v, __shfl_xor(v, 32, 64));
  return v;
}
// 16-lane row-local reductions (DPP only, VALU pipe)
__device__ __forceinline__ float rowsum16(float v) {
  v += dppf<0x121>(v); v += dppf<0x122>(v);
  v += dppf<0x124>(v); v += dppf<0x128>(v);
  return v;
}
__device__ __forceinline__ float rowmax16(float v) {
  v = fmaxf(v, dppf<0x121>(v)); v = fmaxf(v, dppf<0x122>(v));
  v = fmaxf(v, dppf<0x124>(v)); v = fmaxf(v, dppf<0x128>(v));
  return v;
}
__device__ __forceinline__ int rowmin16i(int v) {
  v = min(v, dppi<0x121>(v)); v = min(v, dppi<0x122>(v));
  v = min(v, dppi<0x124>(v)); v = min(v, dppi<0x128>(v));
  return v;
}

// split 8 fp32 -> fp16 h/l (RNE both; h+l captures ~22 significand bits)
__device__ __forceinline__ void split16(const float4& v0, const float4& v1,
                                        ushort* ph, ushort* pl) {
  float xs[8] = {v0.x, v0.y, v0.z, v0.w, v1.x, v1.y, v1.z, v1.w};
  half8 h, l;
#pragma unroll
  for (int j = 0; j < 8; ++j) {
    _Float16 hb = (_Float16)xs[j];
    h[j] = hb;
    float d = xs[j] - (float)hb;
    l[j] = (_Float16)d;
  }
  *(half8*)ph = h;
  *(half8*)pl = l;
}

// Swizzled LDS layout (32-ushort rows): conflict-free staging + frag reads.
__device__ __forceinline__ int lds_idx(int row, int chunk /*0..3*/) {
  int line = row >> 1;
  int c8 = ((row & 1) << 2) | chunk;
  return line * 64 + ((c8 ^ (line & 7)) << 3);
}
// Swizzled LDS layout for 64-ushort rows (Qp tile): row p, 8B-chunk c8 in 0..7.
__device__ __forceinline__ int qoff(int p, int c8) {
  return p * 64 + (((c8 ^ (p & 7)) & 7) << 3);
}

// -------- pre-split: z=0 X -> Xh/Xl, z=1..4 W -> wsp[mi][lvl][WN] -----------
__global__ __launch_bounds__(256) void convert_kernel(
    const float* __restrict__ x,
    const float* __restrict__ W0, const float* __restrict__ W1,
    const float* __restrict__ W2, const float* __restrict__ W3,
    ushort* __restrict__ Xh, ushort* __restrict__ Xl,
    ushort* __restrict__ wsp) {
  int z = blockIdx.y;
  size_t base = (size_t)(blockIdx.x * 256 + threadIdx.x) * 8;
  if (z == 0) {
    float4 v0 = *(const float4*)(x + base);
    float4 v1 = *(const float4*)(x + base + 4);
    split16(v0, v1, Xh + base, Xl + base);
  } else {
    if (base >= WN) return;
    int mi = z - 1;
    const float* s = (mi == 0) ? W0 : (mi == 1) ? W1 : (mi == 2) ? W2 : W3;
    ushort* h = wsp + (size_t)mi * 2 * WN;
    float4 v0 = *(const float4*)(s + base);
    float4 v1 = *(const float4*)(s + base + 4);
    split16(v0, v1, h + base, h + WN + base);
  }
}

// ---------------- split-fp16 MFMA GEMM: dst = (A @ B^T + bias) * scale ------
template <int MODE, int NPROD>
__device__ __forceinline__ void gemm_mfma_body(
    const ushort* __restrict__ Agh, const ushort* __restrict__ Agl,
    const ushort* __restrict__ Bgh, const ushort* __restrict__ Bgl,
    const float* __restrict__ bias, float* __restrict__ dst, float scale,
    int mblk, int nblk, ushort* lds) {
  const int tid = threadIdx.x;
  const int lane = tid & 63;
  const int w = tid >> 6;
  const int wr = w >> 1, wc = w & 1;
  const int lrow = lane & 15, kq = lane >> 4;
  constexpr int ABUF = 4096;
  constexpr int BBUF = 2048;
  ushort* Ahs = lds;
  ushort* Als = Ahs + ABUF;
  ushort* Bhs = lds + 2 * ABUF;
  ushort* Bls = Bhs + BBUF;

  const int arow = tid >> 2;
  const int achk = tid & 3;
  const int aoff0 = lds_idx(arow, achk);
  const int aoff1 = lds_idx(arow + 64, achk);
  const int boff = lds_idx(arow, achk);

  const size_t a0 = (size_t)(mblk + arow) * DM + achk * 8;
  const size_t a1 = (size_t)(mblk + 64 + arow) * DM + achk * 8;
  const size_t b0 = (size_t)(nblk + arow) * DM + achk * 8;

  f32x4 acc[4][2];
#pragma unroll
  for (int i = 0; i < 4; ++i)
#pragma unroll
    for (int j = 0; j < 2; ++j) {
      f32x4 z = {0.f, 0.f, 0.f, 0.f};
      acc[i][j] = z;
    }

  short8 pah0 = *(const short8*)(Agh + a0), pah1 = *(const short8*)(Agh + a1);
  short8 pal0 = *(const short8*)(Agl + a0), pal1 = *(const short8*)(Agl + a1);
  short8 pbh = *(const short8*)(Bgh + b0);
  short8 pbl = *(const short8*)(Bgl + b0);

  for (int k0 = 0; k0 < DM; k0 += 32) {
    __syncthreads();
    *(short8*)&Ahs[aoff0] = pah0; *(short8*)&Ahs[aoff1] = pah1;
    *(short8*)&Als[aoff0] = pal0; *(short8*)&Als[aoff1] = pal1;
    *(short8*)&Bhs[boff] = pbh;
    *(short8*)&Bls[boff] = pbl;
    __syncthreads();
    if (k0 + 32 < DM) {
      pah0 = *(const short8*)(Agh + a0 + k0 + 32);
      pah1 = *(const short8*)(Agh + a1 + k0 + 32);
      pal0 = *(const short8*)(Agl + a0 + k0 + 32);
      pal1 = *(const short8*)(Agl + a1 + k0 + 32);
      pbh = *(const short8*)(Bgh + b0 + k0 + 32);
      pbl = *(const short8*)(Bgl + b0 + k0 + 32);
    }
    half8 afh[4], afl[4];
#pragma unroll
    for (int fi = 0; fi < 4; ++fi) {
      int o = lds_idx(wr * 64 + fi * 16 + lrow, kq);
      afh[fi] = *(const half8*)&Ahs[o];
      afl[fi] = *(const half8*)&Als[o];
    }
#pragma unroll
    for (int fj = 0; fj < 2; ++fj) {
      int o = lds_idx(wc * 32 + fj * 16 + lrow, kq);
      half8 bfh = *(const half8*)&Bhs[o];
      half8 bfl = *(const half8*)&Bls[o];
#pragma unroll
      for (int fi = 0; fi < 4; ++fi) {
        acc[fi][fj] = MFMA_F16(afh[fi], bfh, acc[fi][fj]);
        acc[fi][fj] = MFMA_F16(afl[fi], bfh, acc[fi][fj]);
        acc[fi][fj] = MFMA_F16(afh[fi], bfl, acc[fi][fj]);
        if (NPROD == 4) {
          acc[fi][fj] = MFMA_F16(afl[fi], bfl, acc[fi][fj]);
        }
      }
    }
  }

#pragma unroll
  for (int fj = 0; fj < 2; ++fj) {
    int col = nblk + wc * 32 + fj * 16 + lrow;
    float bv = bias[col];
#pragma unroll
    for (int fi = 0; fi < 4; ++fi) {
#pragma unroll
      for (int reg = 0; reg < 4; ++reg) {
        int row = mblk + wr * 64 + fi * 16 + kq * 4 + reg;
        float o = (acc[fi][fj][reg] + bv) * scale;
        if (MODE == 0) {
          dst[(size_t)row * DM + col] = o;
        } else {
          int b_ = row >> 11, t = row & (TSEQ - 1);
          int h = col >> 6, dd = col & 63;
          dst[(((size_t)(b_ * NH + h)) * TSEQ + t) * HD + dd] = o;
        }
      }
    }
  }
}

// merged q/k/v projection, BN=64, XCD-swizzled.
__global__ __launch_bounds__(256) void qkv_kernel(
    const ushort* __restrict__ Xh, const ushort* __restrict__ Xl,
    const ushort* __restrict__ wsp,
    const float* __restrict__ bq, float* __restrict__ qd,
    const float* __restrict__ bk, float* __restrict__ kd,
    const float* __restrict__ bv, float* __restrict__ vd) {
  __shared__ ushort lds[2 * 4096 + 2 * 2048];  // 24 KB
  int lid = blockIdx.x + 12 * blockIdx.y + 384 * blockIdx.z;
  int swz = (lid & 7) * 144 + (lid >> 3);   // bijective: 1152 % 8 == 0
  int z = swz / 384;
  int rem = swz - z * 384;
  int wy = rem / 12, wx = rem - wy * 12;
  const ushort* Bb = wsp + (size_t)z * 2 * WN;
  if (z == 2) {
    gemm_mfma_body<1, 3>(Xh, Xl, Bb, Bb + WN,
                         bv, vd, 1.0f, wy * 128, wx * 64, lds);
  } else {
    gemm_mfma_body<1, 4>(Xh, Xl, Bb, Bb + WN,
                         z ? bk : bq, z ? kd : qd, z ? 1.0f : 0.125f,
                         wy * 128, wx * 64, lds);
  }
}

__global__ __launch_bounds__(256) void oproj_kernel(
    const ushort* __restrict__ Ph, const ushort* __restrict__ Pl,
    const ushort* __restrict__ wsp,
    const float* __restrict__ bias, float* __restrict__ dst) {
  __shared__ ushort lds[2 * 4096 + 2 * 2048];  // 24 KB
  int lid = blockIdx.x + 12 * blockIdx.y;
  int swz = (lid & 7) * 48 + (lid >> 3);    // bijective: 384 % 8 == 0
  int wy = swz / 12, wx = swz - wy * 12;
  const ushort* Bb = wsp + (size_t)3 * 2 * WN;
  gemm_mfma_body<0, 3>(Ph, Pl, Bb, Bb + WN,
                       bias, dst, 1.0f, wy * 128, wx * 64, lds);
}

// ---------------- window selection: one wave per (bh, t) ----------------
// Gram via fp16 2-way split (err ~2^-22, same proven class as q/k path).
__global__ __launch_bounds__(256) void window_kernel(
    const float* __restrict__ q, const float* __restrict__ k,
    int* __restrict__ sel) {
  int wid = blockIdx.x * 4 + (threadIdx.x >> 6);
  int lane = threadIdx.x & 63;
  int f = lane & 15, kq = lane >> 4;
  int bh = wid >> 11, t = wid & (TSEQ - 1);
  int start = t - 8;
  if (start < 0) start = 0;
  if (start > TSEQ - 16) start = TSEQ - 16;

  const float* kp = k + ((size_t)bh * TSEQ + start + f) * HD + kq * 8;
  const float* qp = q + ((size_t)bh * TSEQ + t) * HD + kq * 8;
  float kv[16], qv[16];
  *(float4*)&kv[0]  = *(const float4*)(kp + 0);
  *(float4*)&kv[4]  = *(const float4*)(kp + 4);
  *(float4*)&kv[8]  = *(const float4*)(kp + 32);
  *(float4*)&kv[12] = *(const float4*)(kp + 36);
  *(float4*)&qv[0]  = *(const float4*)(qp + 0);
  *(float4*)&qv[4]  = *(const float4*)(qp + 4);
  *(float4*)&qv[8]  = *(const float4*)(qp + 32);
  *(float4*)&qv[12] = *(const float4*)(qp + 36);

  float sp = 0.f, np = 0.f;
#pragma unroll
  for (int i = 0; i < 16; ++i) { sp = fmaf(qv[i], kv[i], sp); np = fmaf(kv[i], kv[i], np); }
  sp += __shfl_xor(sp, 16, 64); sp += __shfl_xor(sp, 32, 64);
  np += __shfl_xor(np, 16, 64); np += __shfl_xor(np, 32, 64);
  float nrm = fmaxf(sqrtf(np), 1e-6f);
  float kn[16];
#pragma unroll
  for (int i = 0; i < 16; ++i) kn[i] = kv[i] / nrm;

  half8 h0, l0, h1, l1;
#pragma unroll
  for (int j = 0; j < 8; ++j) {
    _Float16 hb = (_Float16)kn[j];
    h0[j] = hb;
    l0[j] = (_Float16)(kn[j] - (float)hb);
    _Float16 hb1 = (_Float16)kn[8 + j];
    h1[j] = hb1;
    l1[j] = (_Float16)(kn[8 + j] - (float)hb1);
  }
  f32x4 g = {0.f, 0.f, 0.f, 0.f};
  g = MFMA_F16(h0, h0, g); g = MFMA_F16(h1, h1, g);
  g = MFMA_F16(l0, h0, g); g = MFMA_F16(l1, h1, g);
  g = MFMA_F16(h0, l0, g); g = MFMA_F16(h1, l1, g);
  g = MFMA_F16(l0, l0, g); g = MFMA_F16(l1, l1, g);

  int dist = start + f - t; if (dist < 0) dist = -dist;
  float tmp = sp + 0.2f * expf(-(float)dist * 0.125f);

  int* selp = sel + ((size_t)bh * TSEQ + t) * 6;
#pragma unroll
  for (int r = 0; r < 6; ++r) {
    float best = tmp; int bj = f;
    {
      float ov = dppf<0x121>(best); int oi = dppi<0x121>(bj);
      if (ov > best || (ov == best && oi < bj)) { best = ov; bj = oi; }
      ov = dppf<0x122>(best); oi = dppi<0x122>(bj);
      if (ov > best || (ov == best && oi < bj)) { best = ov; bj = oi; }
      ov = dppf<0x124>(best); oi = dppi<0x124>(bj);
      if (ov > best || (ov == best && oi < bj)) { best = ov; bj = oi; }
      ov = dppf<0x128>(best); oi = dppi<0x128>(bj);
      if (ov > best || (ov == best && oi < bj)) { best = ov; bj = oi; }
    }
    if (lane == 0) selp[r] = start + bj;
    if (r < 5) {
      float s01 = (bj & 1) ? g[1] : g[0];
      float s23 = (bj & 1) ? g[3] : g[2];
      float gsel = (bj & 2) ? s23 : s01;
      float grow = __shfl(gsel, ((bj >> 2) << 4) | f, 64);
      tmp -= 0.2f * fmaxf(grow, 0.f);
    }
    if (f == bj) tmp = -1e9f;
  }
}

// -------- prototype queries: emit normalized Qp pre-split fp16 h/l ----------
__global__ __launch_bounds__(256) void qp_kernel(const float* __restrict__ q,
                                                 ushort* __restrict__ Qph,
                                                 ushort* __restrict__ Qpl) {
  int wid = blockIdx.x * 4 + (threadIdx.x >> 6);
  int lane = threadIdx.x & 63;
  int a = wid >> 5, p = wid & 31;
  int t = c_idxp[p];
  float v = 0.5f * (q[((size_t)(2 * a) * TSEQ + t) * HD + lane] +
                    q[((size_t)(2 * a + 1) * TSEQ + t) * HD + lane]);
  float n2 = wsum(v * v);
  float nrm = fmaxf(sqrtf(n2), 1e-6f);
  float qn = v / nrm;
  _Float16 hb = (_Float16)qn;
  float d = qn - (float)hb;
  size_t idx = ((size_t)a * 32 + p) * HD + lane;
  Qph[idx] = __builtin_bit_cast(ushort, hb);
  _Float16 lb = (_Float16)d;
  Qpl[idx] = __builtin_bit_cast(ushort, lb);
}

// -------- S[a][t][p] and u[a][t] via MFMA + DPP row stats -------------------
// Block: 256 thr = 4 waves, handles 64 t's (16 per wave) of head a.
// A = Kbar rows (fp16 2-way split), B = Qp (pre-split). 16 MFMA per wave.
// C layout: t = kq*4+reg, p = ptile*16 + (lane&15) -> p-axis lives in
// contiguous 16-lane DPP rows: all row stats are row-local DPP reductions.
__global__ __launch_bounds__(256) void proto_score_kernel(
    const float* __restrict__ k,
    const ushort* __restrict__ Qph, const ushort* __restrict__ Qpl,
    float* __restrict__ S, float* __restrict__ u) {
  int a = blockIdx.y;
  __shared__ ushort Qh[2048], Ql[2048];
  {
    int p = threadIdx.x >> 3, c8 = threadIdx.x & 7;
    size_t src = (size_t)a * 2048 + p * 64 + c8 * 8;
    *(short8*)&Qh[qoff(p, c8)] = *(const short8*)(Qph + src);
    *(short8*)&Ql[qoff(p, c8)] = *(const short8*)(Qpl + src);
  }
  __syncthreads();

  int wv = threadIdx.x >> 6, lane = threadIdx.x & 63;
  int f = lane & 15, kq = lane >> 4;
  int tbase = blockIdx.x * 64 + wv * 16;
  int tl = tbase + f;  // row this lane LOADS

  const float* k0p = k + ((size_t)(2 * a) * TSEQ + tl) * HD + kq * 8;
  const float* k1p = k + ((size_t)(2 * a + 1) * TSEQ + tl) * HD + kq * 8;
  float km[16];
  {
    float4 x0 = *(const float4*)(k0p + 0),  y0 = *(const float4*)(k1p + 0);
    float4 x1 = *(const float4*)(k0p + 4),  y1 = *(const float4*)(k1p + 4);
    float4 x2 = *(const float4*)(k0p + 32), y2 = *(const float4*)(k1p + 32);
    float4 x3 = *(const float4*)(k0p + 36), y3 = *(const float4*)(k1p + 36);
    km[0] = 0.5f*(x0.x+y0.x); km[1] = 0.5f*(x0.y+y0.y);
    km[2] = 0.5f*(x0.z+y0.z); km[3] = 0.5f*(x0.w+y0.w);
    km[4] = 0.5f*(x1.x+y1.x); km[5] = 0.5f*(x1.y+y1.y);
    km[6] = 0.5f*(x1.z+y1.z); km[7] = 0.5f*(x1.w+y1.w);
    km[8] = 0.5f*(x2.x+y2.x); km[9] = 0.5f*(x2.y+y2.y);
    km[10] = 0.5f*(x2.z+y2.z); km[11] = 0.5f*(x2.w+y2.w);
    km[12] = 0.5f*(x3.x+y3.x); km[13] = 0.5f*(x3.y+y3.y);
    km[14] = 0.5f*(x3.z+y3.z); km[15] = 0.5f*(x3.w+y3.w);
  }
  float np = 0.f;
#pragma unroll
  for (int i = 0; i < 16; ++i) np = fmaf(km[i], km[i], np);
  np += __shfl_xor(np, 16, 64); np += __shfl_xor(np, 32, 64);
  float nrm = fmaxf(sqrtf(np), 1e-6f);

  half8 ah[2], al[2];
#pragma unroll
  for (int s = 0; s < 2; ++s)
#pragma unroll
    for (int j = 0; j < 8; ++j) {
      float x = km[s * 8 + j] / nrm;
      _Float16 hb = (_Float16)x;
      ah[s][j] = hb;
      al[s][j] = (_Float16)(x - (float)hb);
    }

  f32x4 acc0 = {0.f, 0.f, 0.f, 0.f}, acc1 = {0.f, 0.f, 0.f, 0.f};
#pragma unroll
  for (int s = 0; s < 2; ++s) {
    half8 b0h = *(const half8*)&Qh[qoff(f, s * 4 + kq)];
    half8 b0l = *(const half8*)&Ql[qoff(f, s * 4 + kq)];
    half8 b1h = *(const half8*)&Qh[qoff(16 + f, s * 4 + kq)];
    half8 b1l = *(const half8*)&Ql[qoff(16 + f, s * 4 + kq)];
    acc0 = MFMA_F16(ah[s], b0h, acc0);
    acc0 = MFMA_F16(al[s], b0h, acc0);
    acc0 = MFMA_F16(ah[s], b0l, acc0);
    acc0 = MFMA_F16(al[s], b0l, acc0);
    acc1 = MFMA_F16(ah[s], b1h, acc1);
    acc1 = MFMA_F16(al[s], b1h, acc1);
    acc1 = MFMA_F16(ah[s], b1l, acc1);
    acc1 = MFMA_F16(al[s], b1l, acc1);
  }

  // relu + store S + per-row (16-lane DPP) stats; 4 rows in the 4 regs
#pragma unroll
  for (int reg = 0; reg < 4; ++reg) {
    float s0 = fmaxf(acc0[reg], 0.f);   // p = f
    float s1 = fmaxf(acc1[reg], 0.f);   // p = 16 + f
    int t = tbase + kq * 4 + reg;
    size_t srow = ((size_t)a * TSEQ + t) * 32;
    S[srow + f] = s0;
    S[srow + 16 + f] = s1;
    float mean = rowsum16(s0 + s1) / 32.0f;
    float mx = rowmax16(fmaxf(s0, s1));
    float cur0 = s0, cur1 = s1;
    float topsum = 0.f;
#pragma unroll
    for (int r = 0; r < 6; ++r) {
      float mm = rowmax16(fmaxf(cur0, cur1));
      topsum += mm;
      int i0 = rowmin16i((cur0 == mm) ? f : 999);
      int i1 = rowmin16i((cur1 == mm) ? f : 999);
      bool take0 = (i0 < 999);
      if (take0 && f == i0) cur0 = -1e30f;
      if (!take0 && f == i1) cur1 = -1e30f;
    }
    float d0 = s0 - mean, d1 = s1 - mean;
    float sd = sqrtf(rowsum16(d0 * d0 + d1 * d1) / 31.0f);
    float uval = ((1.0f * mean + 0.6f * mx) + 0.4f * (topsum / 6.0f)) + 0.2f * sd;
    if (f == 0) u[(size_t)a * TSEQ + t] = uval;
  }
}

// ---------------- per-head top-12 + greedy facility location ----------------
__global__ void head_select_kernel(const float* __restrict__ u,
                                   const float* __restrict__ S,
                                   int* __restrict__ glob) {
  int a = blockIdx.x;
  int lane = threadIdx.x;
  float uv[32];
#pragma unroll
  for (int c = 0; c < 32; ++c) uv[c] = u[(size_t)a * TSEQ + c * 64 + lane];
  unsigned removed = 0;
  int tidx = 0;
#pragma unroll
  for (int r = 0; r < 12; ++r) {
    float best = -1e30f; int bidx = 1 << 30;
#pragma unroll
    for (int c = 0; c < 32; ++c) {
      if (!((removed >> c) & 1u)) {
        float vv = uv[c]; int gi = c * 64 + lane;
        if (vv > best || (vv == best && gi < bidx)) { best = vv; bidx = gi; }
      }
    }
#pragma unroll
    for (int mS = 1; mS < 64; mS <<= 1) {
      float ov = __shfl_xor(best, mS, 64);
      int oi = __shfl_xor(bidx, mS, 64);
      if (ov > best || (ov == best && oi < bidx)) { best = ov; bidx = oi; }
    }
    if (lane == (bidx & 63)) removed |= 1u << (bidx >> 6);
    if (lane == r) tidx = bidx;
  }
  float srow[12];
#pragma unroll
  for (int r = 0; r < 12; ++r) {
    int tr = __shfl(tidx, r, 64);
    srow[r] = (lane < 32) ? S[((size_t)a * TSEQ + tr) * 32 + lane] : 0.f;
  }
  float m = 0.f;
  unsigned blocked = 0;
#pragma unroll
  for (int g = 0; g < 4; ++g) {
    float gains[12];
#pragma unroll
    for (int r = 0; r < 12; ++r) {
      float gr = (lane < 32) ? fmaxf(srow[r] - m, 0.f) : 0.f;
      gains[r] = wsum(gr);
    }
    float best = -1e30f; int bj = 0;
#pragma unroll
    for (int r = 0; r < 12; ++r) {
      float vv = ((blocked >> r) & 1u) ? -1e9f : gains[r];
      if (vv > best) { best = vv; bj = r; }
    }
    blocked |= 1u << bj;
#pragma unroll
    for (int r = 0; r < 12; ++r) m = (r == bj) ? fmaxf(m, srow[r]) : m;
    int gidx = __shfl(tidx, bj, 64);
    if (lane == 0) glob[a * 4 + g] = gidx;
  }
}

// -------- final 10-candidate attention; emits (h,l) fp16 split directly -----
__global__ __launch_bounds__(256) void attend_kernel(
    const float* __restrict__ q, const float* __restrict__ k,
    const float* __restrict__ v, const int* __restrict__ sel,
    const int* __restrict__ glob, ushort* __restrict__ Ph,
    ushort* __restrict__ Pl) {
  int wid = blockIdx.x * 4 + (threadIdx.x >> 6);
  int lane = threadIdx.x & 63;
  int bh = wid >> 11, t = wid & (TSEQ - 1);
  int h = bh % NH, b = bh / NH;
  float qv = q[((size_t)bh * TSEQ + t) * HD + lane];
  int cand[10];
  const int* selp = sel + ((size_t)bh * TSEQ + t) * 6;
#pragma unroll
  for (int c = 0; c < 6; ++c) cand[c] = selp[c];
#pragma unroll
  for (int c = 0; c < 4; ++c) cand[6 + c] = glob[h * 4 + c];
  float sc[10];
#pragma unroll
  for (int c = 0; c < 10; ++c) {
    float kv = k[((size_t)bh * TSEQ + cand[c]) * HD + lane];
    sc[c] = wsum(qv * kv);
  }
  float mx = sc[0];
#pragma unroll
  for (int c = 1; c < 10; ++c) mx = fmaxf(mx, sc[c]);
  float e[10], den = 0.f;
#pragma unroll
  for (int c = 0; c < 10; ++c) { e[c] = expf(sc[c] - mx); den += e[c]; }
  float o = 0.f;
#pragma unroll
  for (int c = 0; c < 10; ++c) {
    float w = e[c] / den;
    o += w * v[((size_t)bh * TSEQ + cand[c]) * HD + lane];
  }
  size_t idx = ((size_t)b * TSEQ + t) * DM + h * HD + lane;
  _Float16 hb = (_Float16)o;
  float d = o - (float)hb;
  Ph[idx] = __builtin_bit_cast(ushort, hb);
  _Float16 lb = (_Float16)d;
  Pl[idx] = __builtin_bit_cast(ushort, lb);
}

extern "C" void kernel_launch(void* const* d_in, const int* in_sizes, int n_in,
                              void* d_out, int out_size, void* d_ws, size_t ws_size,
                              hipStream_t stream) {
  const float* x  = (const float*)d_in[0];
  const float* Wq = (const float*)d_in[1];
  const float* bq = (const float*)d_in[2];
  const float* Wk = (const float*)d_in[3];
  const float* bk = (const float*)d_in[4];
  const float* Wv = (const float*)d_in[5];
  const float* bv = (const float*)d_in[6];
  const float* Wo = (const float*)d_in[7];
  const float* bo = (const float*)d_in[8];
  float* out = (float*)d_out;

  float* ws = (float*)d_ws;
  const size_t QKV = (size_t)NBH * TSEQ * HD;  // 3145728
  float* qb = ws;
  float* kb = qb + QKV;
  float* vb = kb + QKV;
  float* slotA = vb + QKV;                     // QKV floats: Xh+Xl, later Ph+Pl
  float* QpSlot = slotA + QKV;                 // 24576 floats
  float* S  = QpSlot + (size_t)NH * 32 * HD;
  float* u  = S + (size_t)NH * TSEQ * 32;
  int* sel  = (int*)(u + (size_t)NH * TSEQ);
  int* glob = sel + (size_t)NBH * TSEQ * 6;
  ushort* wsp = (ushort*)(glob + 64);          // 8 x WN ushorts = 9.44 MB

  ushort* Xh = (ushort*)slotA;
  ushort* Xl = Xh + QKV;
  ushort* Ph = Xh;  // reused after last X read (qkv) — attend runs later
  ushort* Pl = Xl;
  ushort* Qph = (ushort*)QpSlot;               // 24576 ushorts
  ushort* Qpl = Qph + (size_t)NH * 32 * HD;    // 24576 ushorts (same slot)

  convert_kernel<<<dim3(1536, 5), 256, 0, stream>>>(
      x, Wq, Wk, Wv, Wo, Xh, Xl, wsp);
  qkv_kernel<<<dim3(12, 32, 3), 256, 0, stream>>>(
      Xh, Xl, wsp, bq, qb, bk, kb, bv, vb);
  window_kernel<<<12288, 256, 0, stream>>>(qb, kb, sel);
  qp_kernel<<<96, 256, 0, stream>>>(qb, Qph, Qpl);
  proto_score_kernel<<<dim3(32, NH), 256, 0, stream>>>(kb, Qph, Qpl, S, u);
  head_select_kernel<<<NH, 64, 0, stream>>>(u, S, glob);
  attend_kernel<<<12288, 256, 0, stream>>>(qb, kb, vb, sel, glob, Ph, Pl);
  oproj_kernel<<<dim3(12, 32), 256, 0, stream>>>(Ph, Pl, wsp, bo, out);
}